// Round 1
// baseline (1076.175 us; speedup 1.0000x reference)
//
#include <hip/hip_runtime.h>
#include <hip/hip_bf16.h>
#include <cstddef>

#define B_   4
#define S_   1500
#define D_   1280
#define H_   20
#define HD_  64
#define M_   (B_*S_)
#define SPAD 1504
#define BIGNEG (-1e30f)

typedef short bf16x8 __attribute__((ext_vector_type(8)));
typedef float f32x4 __attribute__((ext_vector_type(4)));
typedef unsigned short u16;
typedef u16 u16x8 __attribute__((ext_vector_type(8)));

#define MFMA __builtin_amdgcn_mfma_f32_16x16x32_bf16

__device__ __forceinline__ u16 f2bf(float f) {
  union { float f; unsigned u; } x; x.f = f;
  unsigned r = (x.u + 0x7fffu + ((x.u >> 16) & 1u)) >> 16;
  return (u16)r;
}

// ---- fp32 -> bf16 bulk convert (8 elems/thread) ----
__global__ __launch_bounds__(256) void k_conv(const float* __restrict__ X, u16* __restrict__ Y) {
  size_t i = (size_t)blockIdx.x * 256 + threadIdx.x;
  const float4* p = (const float4*)(X + i * 8);
  float4 a = p[0], b = p[1];
  u16x8 v;
  v[0]=f2bf(a.x); v[1]=f2bf(a.y); v[2]=f2bf(a.z); v[3]=f2bf(a.w);
  v[4]=f2bf(b.x); v[5]=f2bf(b.y); v[6]=f2bf(b.z); v[7]=f2bf(b.w);
  *(u16x8*)(Y + i * 8) = v;
}

// ---- W[k][n] fp32 -> Wt[n][k] bf16 transpose ----
__global__ __launch_bounds__(256) void k_trans(const float* __restrict__ W, u16* __restrict__ Wt) {
  __shared__ float t[32][33];
  int n0 = blockIdx.x * 32, k0 = blockIdx.y * 32;
  int tx = threadIdx.x & 31, ty = threadIdx.x >> 5;
  #pragma unroll
  for (int i = ty; i < 32; i += 8) t[i][tx] = W[(size_t)(k0 + i) * D_ + n0 + tx];
  __syncthreads();
  #pragma unroll
  for (int i = ty; i < 32; i += 8) Wt[(size_t)(n0 + i) * D_ + k0 + tx] = f2bf(t[tx][i]);
}

// ---- GEMM: C[M,1280] = A[M,1280] @ W + bias ; A,Wt bf16; per-MODE epilogue ----
// MODE 0: Q = (A@W + b)*0.125 -> bf16 [M][D]
// MODE 1: K = A@W            -> bf16 [M][D]
// MODE 2: V = A@W + b        -> bf16 transposed Vt[b][h][d][SPAD]
// MODE 3: O = A@W + b        -> fp32 d_out [M][D]
template <int MODE>
__global__ __launch_bounds__(256) void k_gemm(const u16* __restrict__ A,
                                              const u16* __restrict__ Wt,
                                              const float* __restrict__ bias,
                                              void* __restrict__ outp) {
  int lane = threadIdx.x & 63, wv = threadIdx.x >> 6;
  int l16 = lane & 15, lg = lane >> 4;
  int m0 = blockIdx.x * 64 + wv * 16;
  int n0 = blockIdx.y * 64;
  int ra = m0 + l16; if (ra > M_ - 1) ra = M_ - 1;
  const u16* ap = A + (size_t)ra * D_ + lg * 8;
  const u16* bp = Wt + (size_t)(n0 + l16) * D_ + lg * 8;
  f32x4 acc[4] = {{0,0,0,0},{0,0,0,0},{0,0,0,0},{0,0,0,0}};
  for (int k = 0; k < D_; k += 32) {
    bf16x8 a  = *(const bf16x8*)(ap + k);
    bf16x8 b0 = *(const bf16x8*)(bp + k);
    bf16x8 b1 = *(const bf16x8*)(bp + (size_t)16 * D_ + k);
    bf16x8 b2 = *(const bf16x8*)(bp + (size_t)32 * D_ + k);
    bf16x8 b3 = *(const bf16x8*)(bp + (size_t)48 * D_ + k);
    acc[0] = MFMA(a, b0, acc[0], 0, 0, 0);
    acc[1] = MFMA(a, b1, acc[1], 0, 0, 0);
    acc[2] = MFMA(a, b2, acc[2], 0, 0, 0);
    acc[3] = MFMA(a, b3, acc[3], 0, 0, 0);
  }
  int rbase = m0 + lg * 4;
  #pragma unroll
  for (int n = 0; n < 4; n++) {
    int col = n0 + n * 16 + l16;
    float bv = (MODE == 1) ? 0.0f : bias[col];
    #pragma unroll
    for (int j = 0; j < 4; j++) {
      int row = rbase + j;
      if (row < M_) {
        float v = acc[n][j] + bv;
        if (MODE == 0) {
          ((u16*)outp)[(size_t)row * D_ + col] = f2bf(v * 0.125f);
        } else if (MODE == 1) {
          ((u16*)outp)[(size_t)row * D_ + col] = f2bf(v);
        } else if (MODE == 2) {
          int b = row / S_, s = row - b * S_;
          int h = col >> 6, d = col & 63;
          ((u16*)outp)[(((size_t)(b * H_ + h)) * HD_ + d) * SPAD + s] = f2bf(v);
        } else {
          ((float*)outp)[(size_t)row * D_ + col] = v;
        }
      }
    }
  }
}

// ---- Flash attention: grid (24 q-macrotiles, 80 b*h), 4 waves x 16 q-rows ----
__global__ __launch_bounds__(256) void k_attn(const u16* __restrict__ Qb,
                                              const u16* __restrict__ Kb,
                                              const u16* __restrict__ Vt,
                                              const float* __restrict__ mask,
                                              u16* __restrict__ Ctx) {
  __shared__ u16 pl[4][16 * 32];
  int lane = threadIdx.x & 63, wv = threadIdx.x >> 6;
  int l16 = lane & 15, lg = lane >> 4;
  int bh = blockIdx.y, b = bh / H_, h = bh % H_;
  int q0 = blockIdx.x * 64 + wv * 16;

  int qr = q0 + l16; if (qr > S_ - 1) qr = S_ - 1;
  const u16* qp = Qb + ((size_t)(b * S_ + qr)) * D_ + h * HD_ + lg * 8;
  bf16x8 aq0 = *(const bf16x8*)(qp);
  bf16x8 aq1 = *(const bf16x8*)(qp + 32);

  const float* mrow = mask + (size_t)b * S_ * S_;
  const u16* kbase = Kb + (size_t)b * S_ * D_ + h * HD_ + lg * 8;
  const u16* vbase = Vt + (size_t)bh * HD_ * SPAD + lg * 8;
  int qrow_base = q0 + lg * 4;

  float m_[4] = {BIGNEG, BIGNEG, BIGNEG, BIGNEG};
  float l_[4] = {0, 0, 0, 0};
  f32x4 acc[4] = {{0,0,0,0},{0,0,0,0},{0,0,0,0},{0,0,0,0}};
  const f32x4 zf = {0, 0, 0, 0};

  for (int k0 = 0; k0 < S_; k0 += 32) {
    int ka = k0 + l16, kb = ka + 16;
    int kac = ka < S_ ? ka : S_ - 1;
    int kbc = kb < S_ ? kb : S_ - 1;
    const u16* kp0 = kbase + (size_t)kac * D_;
    const u16* kp1 = kbase + (size_t)kbc * D_;
    bf16x8 b00 = *(const bf16x8*)(kp0);
    bf16x8 b01 = *(const bf16x8*)(kp0 + 32);
    bf16x8 b10 = *(const bf16x8*)(kp1);
    bf16x8 b11 = *(const bf16x8*)(kp1 + 32);
    f32x4 s0 = MFMA(aq0, b00, zf, 0, 0, 0);
    s0 = MFMA(aq1, b01, s0, 0, 0, 0);
    f32x4 s1 = MFMA(aq0, b10, zf, 0, 0, 0);
    s1 = MFMA(aq1, b11, s1, 0, 0, 0);

    #pragma unroll
    for (int j = 0; j < 4; j++) {
      int qq = qrow_base + j; int qc = qq < S_ ? qq : S_ - 1;
      const float* mr = mrow + (size_t)qc * S_;
      s0[j] = (ka < S_) ? (s0[j] + mr[ka]) : BIGNEG;
      s1[j] = (kb < S_) ? (s1[j] + mr[kb]) : BIGNEG;
    }

    #pragma unroll
    for (int j = 0; j < 4; j++) {
      float tm = fmaxf(s0[j], s1[j]);
      tm = fmaxf(tm, __shfl_xor(tm, 1));
      tm = fmaxf(tm, __shfl_xor(tm, 2));
      tm = fmaxf(tm, __shfl_xor(tm, 4));
      tm = fmaxf(tm, __shfl_xor(tm, 8));
      float mn = fmaxf(m_[j], tm);
      float c  = __expf(m_[j] - mn);
      float p0 = __expf(s0[j] - mn);
      float p1 = __expf(s1[j] - mn);
      float ts = p0 + p1;
      ts += __shfl_xor(ts, 1);
      ts += __shfl_xor(ts, 2);
      ts += __shfl_xor(ts, 4);
      ts += __shfl_xor(ts, 8);
      l_[j] = l_[j] * c + ts;
      m_[j] = mn;
      acc[0][j] *= c; acc[1][j] *= c; acc[2][j] *= c; acc[3][j] *= c;
      pl[wv][(lg * 4 + j) * 32 + l16]      = f2bf(p0);
      pl[wv][(lg * 4 + j) * 32 + 16 + l16] = f2bf(p1);
    }

    bf16x8 pa = *(const bf16x8*)&pl[wv][l16 * 32 + lg * 8];
    #pragma unroll
    for (int n = 0; n < 4; n++) {
      bf16x8 bv = *(const bf16x8*)(vbase + (size_t)(n * 16 + l16) * SPAD + k0);
      acc[n] = MFMA(pa, bv, acc[n], 0, 0, 0);
    }
  }

  #pragma unroll
  for (int n = 0; n < 4; n++) {
    #pragma unroll
    for (int j = 0; j < 4; j++) {
      int row = qrow_base + j;
      if (row < S_) {
        float v = acc[n][j] / l_[j];
        Ctx[((size_t)(b * S_ + row)) * D_ + h * HD_ + n * 16 + l16] = f2bf(v);
      }
    }
  }
}

extern "C" void kernel_launch(void* const* d_in, const int* in_sizes, int n_in,
                              void* d_out, int out_size, void* d_ws, size_t ws_size,
                              hipStream_t stream) {
  const float* hs   = (const float*)d_in[0];
  const float* mask = (const float*)d_in[1];
  const float* q_w  = (const float*)d_in[2];
  const float* q_b  = (const float*)d_in[3];
  const float* k_w  = (const float*)d_in[4];
  const float* v_w  = (const float*)d_in[5];
  const float* v_b  = (const float*)d_in[6];
  const float* o_w  = (const float*)d_in[7];
  const float* o_b  = (const float*)d_in[8];
  float* out = (float*)d_out;

  char* w = (char*)d_ws;
  const size_t XD = (size_t)M_ * D_;          // 7,680,000 elems
  const size_t WD = (size_t)D_ * D_;          // 1,638,400 elems
  u16* Xb  = (u16*)(w);                 w += XD * 2;
  u16* Wtq = (u16*)(w);                 w += WD * 2;
  u16* Wtk = (u16*)(w);                 w += WD * 2;
  u16* Wtv = (u16*)(w);                 w += WD * 2;
  u16* Wto = (u16*)(w);                 w += WD * 2;
  u16* Qb  = (u16*)(w);                 w += XD * 2;
  u16* Kb  = (u16*)(w);                 w += XD * 2;
  u16* Vt  = (u16*)(w);                 w += (size_t)B_ * H_ * HD_ * SPAD * 2;
  u16* Ctx = (u16*)(w);                 w += XD * 2;

  // 1) convert X
  k_conv<<<dim3(3750), dim3(256), 0, stream>>>(hs, Xb);
  // 2) transpose+convert weights
  k_trans<<<dim3(40, 40), dim3(256), 0, stream>>>(q_w, Wtq);
  k_trans<<<dim3(40, 40), dim3(256), 0, stream>>>(k_w, Wtk);
  k_trans<<<dim3(40, 40), dim3(256), 0, stream>>>(v_w, Wtv);
  k_trans<<<dim3(40, 40), dim3(256), 0, stream>>>(o_w, Wto);
  // 3) projections
  dim3 gg(94, 20);
  k_gemm<0><<<gg, dim3(256), 0, stream>>>(Xb, Wtq, q_b, Qb);
  k_gemm<1><<<gg, dim3(256), 0, stream>>>(Xb, Wtk, nullptr, Kb);
  k_gemm<2><<<gg, dim3(256), 0, stream>>>(Xb, Wtv, v_b, Vt);
  // 4) attention
  k_attn<<<dim3(24, 80), dim3(256), 0, stream>>>(Qb, Kb, Vt, mask, Ctx);
  // 5) output projection
  k_gemm<3><<<gg, dim3(256), 0, stream>>>(Ctx, Wto, o_b, out);
}

// Round 2
// 740.790 us; speedup vs baseline: 1.4527x; 1.4527x over previous
//
#include <hip/hip_runtime.h>
#include <hip/hip_bf16.h>
#include <cstddef>

#define B_   4
#define S_   1500
#define D_   1280
#define H_   20
#define HD_  64
#define M_   (B_*S_)
#define SPAD 1536
#define BIGNEG (-1e30f)

typedef short bf16x8 __attribute__((ext_vector_type(8)));
typedef float f32x4 __attribute__((ext_vector_type(4)));
typedef unsigned short u16;
typedef u16 u16x8 __attribute__((ext_vector_type(8)));

#define MFMA __builtin_amdgcn_mfma_f32_16x16x32_bf16

__device__ __forceinline__ u16 f2bf(float f) {
  union { float f; unsigned u; } x; x.f = f;
  unsigned r = (x.u + 0x7fffu + ((x.u >> 16) & 1u)) >> 16;
  return (u16)r;
}

// ---- fp32 -> bf16 bulk convert (8 elems/thread) ----
__global__ __launch_bounds__(256) void k_conv(const float* __restrict__ X, u16* __restrict__ Y) {
  size_t i = (size_t)blockIdx.x * 256 + threadIdx.x;
  const float4* p = (const float4*)(X + i * 8);
  float4 a = p[0], b = p[1];
  u16x8 v;
  v[0]=f2bf(a.x); v[1]=f2bf(a.y); v[2]=f2bf(a.z); v[3]=f2bf(a.w);
  v[4]=f2bf(b.x); v[5]=f2bf(b.y); v[6]=f2bf(b.z); v[7]=f2bf(b.w);
  *(u16x8*)(Y + i * 8) = v;
}

// ---- W[k][n] fp32 -> Wt[n][k] bf16 transpose ----
__global__ __launch_bounds__(256) void k_trans(const float* __restrict__ W, u16* __restrict__ Wt) {
  __shared__ float t[32][33];
  int n0 = blockIdx.x * 32, k0 = blockIdx.y * 32;
  int tx = threadIdx.x & 31, ty = threadIdx.x >> 5;
  #pragma unroll
  for (int i = ty; i < 32; i += 8) t[i][tx] = W[(size_t)(k0 + i) * D_ + n0 + tx];
  __syncthreads();
  #pragma unroll
  for (int i = ty; i < 32; i += 8) Wt[(size_t)(n0 + i) * D_ + k0 + tx] = f2bf(t[tx][i]);
}

// ---- Vb[M][D] bf16 -> Vt[bh][d][SPAD] bf16 (per-head transpose) ----
__global__ __launch_bounds__(256) void k_vtrans(const u16* __restrict__ Vb, u16* __restrict__ Vt) {
  __shared__ u16 t[128][72];
  int bh = blockIdx.x, b = bh / H_, h = bh % H_;
  int s0 = blockIdx.y * 128;
  int tid = threadIdx.x;
  #pragma unroll
  for (int r = 0; r < 4; r++) {
    int sl = r * 32 + (tid >> 3);
    int s = s0 + sl; if (s > S_ - 1) s = S_ - 1;
    bf16x8 v = *(const bf16x8*)(Vb + ((size_t)(b * S_ + s)) * D_ + h * HD_ + (tid & 7) * 8);
    *(bf16x8*)&t[sl][(tid & 7) * 8] = v;
  }
  __syncthreads();
  #pragma unroll
  for (int r = 0; r < 4; r++) {
    int d = r * 16 + (tid >> 4);
    int ss = (tid & 15) * 8;
    u16x8 o;
    #pragma unroll
    for (int q = 0; q < 8; q++) o[q] = t[ss + q][d];
    *(u16x8*)(Vt + ((size_t)bh * HD_ + d) * SPAD + s0 + ss) = o;
  }
}

// ---- GEMM: C[M,1280] = A[M,1280] @ Wt^T + bias ; 128x128 tile, BK=64 ----
// MODE 0: Q = (A@W + b)*0.125 -> bf16 ; MODE 1: K -> bf16 (no bias)
// MODE 2: V = A@W + b -> bf16 ; MODE 3: O = A@W + b -> fp32 d_out
template <int MODE>
__global__ __launch_bounds__(256) void k_gemm(const u16* __restrict__ A,
                                              const u16* __restrict__ Wt,
                                              const float* __restrict__ bias,
                                              void* __restrict__ outp) {
  __shared__ u16 As[128 * 64];
  __shared__ u16 Bs[128 * 64];
  int tid = threadIdx.x;
  int lane = tid & 63;
  int wv = tid >> 6;
  int l16 = lane & 15, lg = lane >> 4;
  int wr = wv >> 1, wc = wv & 1;
  int m0 = blockIdx.x * 128, n0 = blockIdx.y * 128;

  int srow = tid >> 3, scol = tid & 7;
  int wcol8 = ((scol ^ (srow & 7))) * 8;   // swizzled u16 col for LDS write

  f32x4 acc[4][4] = {};

  for (int k0 = 0; k0 < D_; k0 += 64) {
    bf16x8 ta[4], tb[4];
    #pragma unroll
    for (int c = 0; c < 4; c++) {
      int row = srow + c * 32;
      int ar = m0 + row; if (ar > M_ - 1) ar = M_ - 1;
      ta[c] = *(const bf16x8*)(A  + (size_t)ar * D_ + k0 + scol * 8);
      tb[c] = *(const bf16x8*)(Wt + (size_t)(n0 + row) * D_ + k0 + scol * 8);
    }
    __syncthreads();
    #pragma unroll
    for (int c = 0; c < 4; c++) {
      int row = srow + c * 32;
      *(bf16x8*)&As[row * 64 + wcol8] = ta[c];
      *(bf16x8*)&Bs[row * 64 + wcol8] = tb[c];
    }
    __syncthreads();
    #pragma unroll
    for (int kk = 0; kk < 2; kk++) {
      int pcol = ((kk * 4 + lg) ^ (l16 & 7)) * 8;
      bf16x8 af[4], bf[4];
      #pragma unroll
      for (int m = 0; m < 4; m++)
        af[m] = *(const bf16x8*)&As[(wr * 64 + m * 16 + l16) * 64 + pcol];
      #pragma unroll
      for (int n = 0; n < 4; n++)
        bf[n] = *(const bf16x8*)&Bs[(wc * 64 + n * 16 + l16) * 64 + pcol];
      __builtin_amdgcn_s_setprio(1);
      #pragma unroll
      for (int m = 0; m < 4; m++)
        #pragma unroll
        for (int n = 0; n < 4; n++)
          acc[m][n] = MFMA(af[m], bf[n], acc[m][n], 0, 0, 0);
      __builtin_amdgcn_s_setprio(0);
    }
  }

  #pragma unroll
  for (int m = 0; m < 4; m++) {
    int row0 = m0 + wr * 64 + m * 16 + lg * 4;
    #pragma unroll
    for (int n = 0; n < 4; n++) {
      int col = n0 + wc * 64 + n * 16 + l16;
      float bv = (MODE == 1) ? 0.0f : bias[col];
      #pragma unroll
      for (int j = 0; j < 4; j++) {
        int row = row0 + j;
        if (row < M_) {
          float v = acc[m][n][j] + bv;
          if (MODE == 0)      ((u16*)outp)[(size_t)row * D_ + col] = f2bf(v * 0.125f);
          else if (MODE == 3) ((float*)outp)[(size_t)row * D_ + col] = v;
          else                ((u16*)outp)[(size_t)row * D_ + col] = f2bf(v);
        }
      }
    }
  }
}

// ---- Flash attention: grid (24 q-tiles, 80 b*h), 4 waves x 16 q-rows, KVBLK=64 ----
__global__ __launch_bounds__(256) void k_attn(const u16* __restrict__ Qb,
                                              const u16* __restrict__ Kb,
                                              const u16* __restrict__ Vt,
                                              const float* __restrict__ mask,
                                              u16* __restrict__ Ctx) {
  __shared__ u16 pl[4][16 * 72];
  int lane = threadIdx.x & 63, wv = threadIdx.x >> 6;
  int l16 = lane & 15, lg = lane >> 4;
  int bh = blockIdx.y, b = bh / H_, h = bh % H_;
  int q0 = blockIdx.x * 64 + wv * 16;

  int qr = q0 + l16; if (qr > S_ - 1) qr = S_ - 1;
  const u16* qp = Qb + ((size_t)(b * S_ + qr)) * D_ + h * HD_ + lg * 8;
  bf16x8 aq0 = *(const bf16x8*)(qp);
  bf16x8 aq1 = *(const bf16x8*)(qp + 32);

  const u16* kbase = Kb + (size_t)b * S_ * D_ + h * HD_ + lg * 8;
  const u16* vbase = Vt + (size_t)bh * HD_ * SPAD + lg * 8;
  int qrow_base = q0 + lg * 4;

  const float* mq[4];
  #pragma unroll
  for (int j = 0; j < 4; j++) {
    int qq = qrow_base + j; int qc = qq < S_ ? qq : S_ - 1;
    mq[j] = mask + (size_t)b * S_ * S_ + (size_t)qc * S_;
  }

  float m_[4] = {BIGNEG, BIGNEG, BIGNEG, BIGNEG};
  float l_[4] = {0, 0, 0, 0};
  f32x4 acc[4] = {};
  const f32x4 zf = {0, 0, 0, 0};

  for (int k0 = 0; k0 < S_; k0 += 64) {
    f32x4 s[4];
    __builtin_amdgcn_s_setprio(1);
    #pragma unroll
    for (int sub = 0; sub < 4; sub++) {
      int ka = k0 + sub * 16 + l16;
      int kc = ka < S_ ? ka : S_ - 1;
      const u16* kp = kbase + (size_t)kc * D_;
      bf16x8 kf0 = *(const bf16x8*)(kp);
      bf16x8 kf1 = *(const bf16x8*)(kp + 32);
      s[sub] = MFMA(aq0, kf0, zf, 0, 0, 0);
      s[sub] = MFMA(aq1, kf1, s[sub], 0, 0, 0);
    }
    __builtin_amdgcn_s_setprio(0);

    #pragma unroll
    for (int sub = 0; sub < 4; sub++) {
      int ka = k0 + sub * 16 + l16;
      bool kv = ka < S_;
      #pragma unroll
      for (int j = 0; j < 4; j++)
        s[sub][j] = kv ? (s[sub][j] + mq[j][ka]) : BIGNEG;
    }

    #pragma unroll
    for (int j = 0; j < 4; j++) {
      float tm = fmaxf(fmaxf(s[0][j], s[1][j]), fmaxf(s[2][j], s[3][j]));
      tm = fmaxf(tm, __shfl_xor(tm, 1));
      tm = fmaxf(tm, __shfl_xor(tm, 2));
      tm = fmaxf(tm, __shfl_xor(tm, 4));
      tm = fmaxf(tm, __shfl_xor(tm, 8));
      float mn = fmaxf(m_[j], tm);
      float c  = __expf(m_[j] - mn);
      float p0 = __expf(s[0][j] - mn);
      float p1 = __expf(s[1][j] - mn);
      float p2 = __expf(s[2][j] - mn);
      float p3 = __expf(s[3][j] - mn);
      float ts = (p0 + p1) + (p2 + p3);
      ts += __shfl_xor(ts, 1);
      ts += __shfl_xor(ts, 2);
      ts += __shfl_xor(ts, 4);
      ts += __shfl_xor(ts, 8);
      l_[j] = l_[j] * c + ts;
      bool resc = mn > m_[j];
      m_[j] = mn;
      if (resc) { acc[0][j] *= c; acc[1][j] *= c; acc[2][j] *= c; acc[3][j] *= c; }
      int prow = (lg * 4 + j) * 72;
      pl[wv][prow + l16]      = f2bf(p0);
      pl[wv][prow + 16 + l16] = f2bf(p1);
      pl[wv][prow + 32 + l16] = f2bf(p2);
      pl[wv][prow + 48 + l16] = f2bf(p3);
    }

    bf16x8 pa0 = *(const bf16x8*)&pl[wv][l16 * 72 + lg * 8];
    bf16x8 pa1 = *(const bf16x8*)&pl[wv][l16 * 72 + 32 + lg * 8];
    __builtin_amdgcn_s_setprio(1);
    #pragma unroll
    for (int n = 0; n < 4; n++) {
      const u16* vp = vbase + (size_t)(n * 16 + l16) * SPAD + k0;
      bf16x8 bv0 = *(const bf16x8*)(vp);
      bf16x8 bv1 = *(const bf16x8*)(vp + 32);
      acc[n] = MFMA(pa0, bv0, acc[n], 0, 0, 0);
      acc[n] = MFMA(pa1, bv1, acc[n], 0, 0, 0);
    }
    __builtin_amdgcn_s_setprio(0);
  }

  #pragma unroll
  for (int n = 0; n < 4; n++) {
    #pragma unroll
    for (int j = 0; j < 4; j++) {
      int row = qrow_base + j;
      if (row < S_) {
        float v = acc[n][j] / l_[j];
        Ctx[((size_t)(b * S_ + row)) * D_ + h * HD_ + n * 16 + l16] = f2bf(v);
      }
    }
  }
}

extern "C" void kernel_launch(void* const* d_in, const int* in_sizes, int n_in,
                              void* d_out, int out_size, void* d_ws, size_t ws_size,
                              hipStream_t stream) {
  const float* hs   = (const float*)d_in[0];
  const float* mask = (const float*)d_in[1];
  const float* q_w  = (const float*)d_in[2];
  const float* q_b  = (const float*)d_in[3];
  const float* k_w  = (const float*)d_in[4];
  const float* v_w  = (const float*)d_in[5];
  const float* v_b  = (const float*)d_in[6];
  const float* o_w  = (const float*)d_in[7];
  const float* o_b  = (const float*)d_in[8];
  float* out = (float*)d_out;

  char* w = (char*)d_ws;
  const size_t XD = (size_t)M_ * D_;
  const size_t WD = (size_t)D_ * D_;
  u16* Xb  = (u16*)(w);                 w += XD * 2;
  u16* Wtq = (u16*)(w);                 w += WD * 2;
  u16* Wtk = (u16*)(w);                 w += WD * 2;
  u16* Wtv = (u16*)(w);                 w += WD * 2;
  u16* Wto = (u16*)(w);                 w += WD * 2;
  u16* Qb  = (u16*)(w);                 w += XD * 2;
  u16* Kb  = (u16*)(w);                 w += XD * 2;
  u16* Vb  = (u16*)(w);                 w += XD * 2;
  u16* Vt  = (u16*)(w);                 w += (size_t)B_ * H_ * HD_ * SPAD * 2;
  u16* Ctx = Xb;   // alias: Xb is dead once the V projection has run

  k_conv<<<dim3(3750), dim3(256), 0, stream>>>(hs, Xb);
  k_trans<<<dim3(40, 40), dim3(256), 0, stream>>>(q_w, Wtq);
  k_trans<<<dim3(40, 40), dim3(256), 0, stream>>>(k_w, Wtk);
  k_trans<<<dim3(40, 40), dim3(256), 0, stream>>>(v_w, Wtv);
  k_trans<<<dim3(40, 40), dim3(256), 0, stream>>>(o_w, Wto);

  dim3 gg(47, 10);
  k_gemm<0><<<gg, dim3(256), 0, stream>>>(Xb, Wtq, q_b, Qb);
  k_gemm<1><<<gg, dim3(256), 0, stream>>>(Xb, Wtk, nullptr, Kb);
  k_gemm<2><<<gg, dim3(256), 0, stream>>>(Xb, Wtv, v_b, Vb);
  k_vtrans<<<dim3(80, 12), dim3(256), 0, stream>>>(Vb, Vt);

  k_attn<<<dim3(24, 80), dim3(256), 0, stream>>>(Qb, Kb, Vt, mask, Ctx);

  k_gemm<3><<<gg, dim3(256), 0, stream>>>(Ctx, Wto, o_b, out);
}

// Round 3
// 548.809 us; speedup vs baseline: 1.9609x; 1.3498x over previous
//
#include <hip/hip_runtime.h>
#include <hip/hip_bf16.h>
#include <cstddef>

#define B_   4
#define S_   1500
#define D_   1280
#define H_   20
#define HD_  64
#define M_   (B_*S_)
#define SPAD 1536
#define BIGNEG (-1e30f)
#define LOG2E 1.44269504088896340736f

typedef short bf16x8 __attribute__((ext_vector_type(8)));
typedef float f32x4 __attribute__((ext_vector_type(4)));
typedef unsigned short u16;
typedef u16 u16x8 __attribute__((ext_vector_type(8)));

#define MFMA __builtin_amdgcn_mfma_f32_16x16x32_bf16

__device__ __forceinline__ u16 f2bf(float f) {
  union { float f; unsigned u; } x; x.f = f;
  unsigned r = (x.u + 0x7fffu + ((x.u >> 16) & 1u)) >> 16;
  return (u16)r;
}

__device__ __forceinline__ unsigned cvtpk(float a, float b) {
  unsigned r;
  asm volatile("v_cvt_pk_bf16_f32 %0, %1, %2" : "=v"(r) : "v"(a), "v"(b));
  return r;
}

// ---- fp32 -> bf16 bulk convert (8 elems/thread) ----
__global__ __launch_bounds__(256) void k_conv(const float* __restrict__ X, u16* __restrict__ Y) {
  size_t i = (size_t)blockIdx.x * 256 + threadIdx.x;
  const float4* p = (const float4*)(X + i * 8);
  float4 a = p[0], b = p[1];
  u16x8 v;
  v[0]=f2bf(a.x); v[1]=f2bf(a.y); v[2]=f2bf(a.z); v[3]=f2bf(a.w);
  v[4]=f2bf(b.x); v[5]=f2bf(b.y); v[6]=f2bf(b.z); v[7]=f2bf(b.w);
  *(u16x8*)(Y + i * 8) = v;
}

// ---- W[k][n] fp32 -> Wt[n][k] bf16 transpose ----
__global__ __launch_bounds__(256) void k_trans(const float* __restrict__ W, u16* __restrict__ Wt) {
  __shared__ float t[32][33];
  int n0 = blockIdx.x * 32, k0 = blockIdx.y * 32;
  int tx = threadIdx.x & 31, ty = threadIdx.x >> 5;
  #pragma unroll
  for (int i = ty; i < 32; i += 8) t[i][tx] = W[(size_t)(k0 + i) * D_ + n0 + tx];
  __syncthreads();
  #pragma unroll
  for (int i = ty; i < 32; i += 8) Wt[(size_t)(n0 + i) * D_ + k0 + tx] = f2bf(t[tx][i]);
}

// ---- Vb[M][D] bf16 -> Vt[bh][d][SPAD] bf16 (per-head transpose) ----
__global__ __launch_bounds__(256) void k_vtrans(const u16* __restrict__ Vb, u16* __restrict__ Vt) {
  __shared__ u16 t[128][72];
  int bh = blockIdx.x, b = bh / H_, h = bh % H_;
  int s0 = blockIdx.y * 128;
  int tid = threadIdx.x;
  #pragma unroll
  for (int r = 0; r < 4; r++) {
    int sl = r * 32 + (tid >> 3);
    int s = s0 + sl; if (s > S_ - 1) s = S_ - 1;
    bf16x8 v = *(const bf16x8*)(Vb + ((size_t)(b * S_ + s)) * D_ + h * HD_ + (tid & 7) * 8);
    *(bf16x8*)&t[sl][(tid & 7) * 8] = v;
  }
  __syncthreads();
  #pragma unroll
  for (int r = 0; r < 4; r++) {
    int d = r * 16 + (tid >> 4);
    int ss = (tid & 15) * 8;
    u16x8 o;
    #pragma unroll
    for (int q = 0; q < 8; q++) o[q] = t[ss + q][d];
    *(u16x8*)(Vt + ((size_t)bh * HD_ + d) * SPAD + s0 + ss) = o;
  }
}

// ---- GEMM: C[M,1280] = A[M,1280] @ Wt^T + bias ; 128x128 tile, BK=64 ----
// MODE 0: Q = (A@W + b)*0.125*log2e -> bf16 ; MODE 1: K -> bf16 (no bias)
// MODE 2: V = A@W + b -> bf16 ; MODE 3: O = A@W + b -> fp32 d_out
template <int MODE>
__global__ __launch_bounds__(256) void k_gemm(const u16* __restrict__ A,
                                              const u16* __restrict__ Wt,
                                              const float* __restrict__ bias,
                                              void* __restrict__ outp) {
  __shared__ u16 As[128 * 64];
  __shared__ u16 Bs[128 * 64];
  int tid = threadIdx.x;
  int lane = tid & 63;
  int wv = tid >> 6;
  int l16 = lane & 15, lg = lane >> 4;
  int wr = wv >> 1, wc = wv & 1;
  int m0 = blockIdx.x * 128, n0 = blockIdx.y * 128;

  int srow = tid >> 3, scol = tid & 7;
  int wcol8 = ((scol ^ (srow & 7))) * 8;   // swizzled u16 col for LDS write

  f32x4 acc[4][4] = {};

  for (int k0 = 0; k0 < D_; k0 += 64) {
    bf16x8 ta[4], tb[4];
    #pragma unroll
    for (int c = 0; c < 4; c++) {
      int row = srow + c * 32;
      int ar = m0 + row; if (ar > M_ - 1) ar = M_ - 1;
      ta[c] = *(const bf16x8*)(A  + (size_t)ar * D_ + k0 + scol * 8);
      tb[c] = *(const bf16x8*)(Wt + (size_t)(n0 + row) * D_ + k0 + scol * 8);
    }
    __syncthreads();
    #pragma unroll
    for (int c = 0; c < 4; c++) {
      int row = srow + c * 32;
      *(bf16x8*)&As[row * 64 + wcol8] = ta[c];
      *(bf16x8*)&Bs[row * 64 + wcol8] = tb[c];
    }
    __syncthreads();
    #pragma unroll
    for (int kk = 0; kk < 2; kk++) {
      int pcol = ((kk * 4 + lg) ^ (l16 & 7)) * 8;
      bf16x8 af[4], bf[4];
      #pragma unroll
      for (int m = 0; m < 4; m++)
        af[m] = *(const bf16x8*)&As[(wr * 64 + m * 16 + l16) * 64 + pcol];
      #pragma unroll
      for (int n = 0; n < 4; n++)
        bf[n] = *(const bf16x8*)&Bs[(wc * 64 + n * 16 + l16) * 64 + pcol];
      __builtin_amdgcn_s_setprio(1);
      #pragma unroll
      for (int m = 0; m < 4; m++)
        #pragma unroll
        for (int n = 0; n < 4; n++)
          acc[m][n] = MFMA(af[m], bf[n], acc[m][n], 0, 0, 0);
      __builtin_amdgcn_s_setprio(0);
    }
  }

  #pragma unroll
  for (int m = 0; m < 4; m++) {
    int row0 = m0 + wr * 64 + m * 16 + lg * 4;
    #pragma unroll
    for (int n = 0; n < 4; n++) {
      int col = n0 + wc * 64 + n * 16 + l16;
      float bv = (MODE == 1) ? 0.0f : bias[col];
      #pragma unroll
      for (int j = 0; j < 4; j++) {
        int row = row0 + j;
        if (row < M_) {
          float v = acc[m][n][j] + bv;
          if (MODE == 0)      ((u16*)outp)[(size_t)row * D_ + col] = f2bf(v * (0.125f * LOG2E));
          else if (MODE == 3) ((float*)outp)[(size_t)row * D_ + col] = v;
          else                ((u16*)outp)[(size_t)row * D_ + col] = f2bf(v);
        }
      }
    }
  }
}

// ---- Flash attention, swapped-QK layout: lane l16 owns q-row l16's scores ----
// grid (24 q-tiles, 80 b*h), 4 independent waves x 16 q-rows, KVBLK=64
__global__ __launch_bounds__(256) void k_attn(const u16* __restrict__ Qb,
                                              const u16* __restrict__ Kb,
                                              const u16* __restrict__ Vt,
                                              const float* __restrict__ mask,
                                              u16* __restrict__ Ctx) {
  __shared__ u16 pl[4][16 * 72];
  int lane = threadIdx.x & 63, wv = threadIdx.x >> 6;
  int l16 = lane & 15, lg = lane >> 4;
  int bh = blockIdx.y, b = bh / H_, h = bh % H_;
  int qw0 = blockIdx.x * 64 + wv * 16;

  int qr = qw0 + l16; if (qr > S_ - 1) qr = S_ - 1;
  const u16* qp = Qb + ((size_t)(b * S_ + qr)) * D_ + h * HD_ + lg * 8;
  bf16x8 aq0 = *(const bf16x8*)(qp);        // Q[qr][lg*8..+7]  (pre-scaled by 0.125*log2e)
  bf16x8 aq1 = *(const bf16x8*)(qp + 32);

  const float* mrow = mask + (size_t)b * S_ * S_ + (size_t)qr * S_;  // lane's own q-row
  const u16* kbase = Kb + (size_t)b * S_ * D_ + h * HD_ + lg * 8;
  const u16* vbase = Vt + (size_t)bh * HD_ * SPAD + lg * 8;

  char* plw = (char*)&pl[wv][0] + l16 * 144 + lg * 8;   // write base (row l16)
  const char* plr = (const char*)&pl[wv][0] + l16 * 144 + lg * 16;  // read base

  float m_ = BIGNEG, l_ = 0.0f;
  f32x4 acc[4] = {};
  const f32x4 zf = {0, 0, 0, 0};

  for (int k0 = 0; k0 < 1536; k0 += 64) {
    f32x4 s[4];
    // QK^T swapped: s[sub][j] = score2[q=l16][key=k0+sub*16+lg*4+j]
    #pragma unroll
    for (int sub = 0; sub < 4; sub++) {
      int kr = k0 + sub * 16 + l16;
      int kc = kr < S_ ? kr : S_ - 1;
      const u16* kp = kbase + (size_t)kc * D_;
      bf16x8 kf0 = *(const bf16x8*)(kp);
      bf16x8 kf1 = *(const bf16x8*)(kp + 32);
      s[sub] = MFMA(kf0, aq0, zf, 0, 0, 0);
      s[sub] = MFMA(kf1, aq1, s[sub], 0, 0, 0);
    }
    // mask (x log2e) + key validity
    #pragma unroll
    for (int sub = 0; sub < 4; sub++) {
      int kb4 = k0 + sub * 16 + lg * 4;
      if (kb4 < S_) {   // S_%4==0 so whole float4 valid
        float4 mv = *(const float4*)(mrow + kb4);
        s[sub][0] = fmaf(mv.x, LOG2E, s[sub][0]);
        s[sub][1] = fmaf(mv.y, LOG2E, s[sub][1]);
        s[sub][2] = fmaf(mv.z, LOG2E, s[sub][2]);
        s[sub][3] = fmaf(mv.w, LOG2E, s[sub][3]);
      } else {
        s[sub][0] = BIGNEG; s[sub][1] = BIGNEG; s[sub][2] = BIGNEG; s[sub][3] = BIGNEG;
      }
    }
    // row max: in-lane tree (16) + 2 cross-group shuffles
    float t0 = fmaxf(fmaxf(s[0][0], s[0][1]), fmaxf(s[0][2], s[0][3]));
    float t1 = fmaxf(fmaxf(s[1][0], s[1][1]), fmaxf(s[1][2], s[1][3]));
    float t2 = fmaxf(fmaxf(s[2][0], s[2][1]), fmaxf(s[2][2], s[2][3]));
    float t3 = fmaxf(fmaxf(s[3][0], s[3][1]), fmaxf(s[3][2], s[3][3]));
    float rmax = fmaxf(fmaxf(t0, t1), fmaxf(t2, t3));
    rmax = fmaxf(rmax, __shfl_xor(rmax, 16));
    rmax = fmaxf(rmax, __shfl_xor(rmax, 32));
    float mn = fmaxf(m_, rmax);
    // defer-max (T13): skip rescale while growth <= 8 (log2 units)
    if (!__all(mn - m_ <= 8.0f)) {
      float c = __builtin_amdgcn_exp2f(m_ - mn);
      m_ = mn;
      l_ *= c;
      #pragma unroll
      for (int j = 0; j < 4; j++) {
        float cj = __shfl(c, lg * 4 + j);   // rescale factor of acc's q-row
        acc[0][j] *= cj; acc[1][j] *= cj; acc[2][j] *= cj; acc[3][j] *= cj;
      }
    }
    // p = 2^(s - m_), row sum, pack to bf16, stash in LDS
    #pragma unroll
    for (int sub = 0; sub < 4; sub++)
      #pragma unroll
      for (int j = 0; j < 4; j++)
        s[sub][j] = __builtin_amdgcn_exp2f(s[sub][j] - m_);
    float a0 = (s[0][0] + s[0][1]) + (s[0][2] + s[0][3]);
    float a1 = (s[1][0] + s[1][1]) + (s[1][2] + s[1][3]);
    float a2 = (s[2][0] + s[2][1]) + (s[2][2] + s[2][3]);
    float a3 = (s[3][0] + s[3][1]) + (s[3][2] + s[3][3]);
    float rs = (a0 + a1) + (a2 + a3);
    rs += __shfl_xor(rs, 16);
    rs += __shfl_xor(rs, 32);
    l_ += rs;
    #pragma unroll
    for (int sub = 0; sub < 4; sub++) {
      uint2 w;
      w.x = cvtpk(s[sub][0], s[sub][1]);
      w.y = cvtpk(s[sub][2], s[sub][3]);
      *(uint2*)(plw + sub * 32) = w;
    }
    bf16x8 pa0 = *(const bf16x8*)(plr);        // P[q=l16][keys lg*8..+7]
    bf16x8 pa1 = *(const bf16x8*)(plr + 64);   // keys 32+lg*8..+7
    #pragma unroll
    for (int n = 0; n < 4; n++) {
      const u16* vp = vbase + (size_t)(n * 16 + l16) * SPAD + k0;
      bf16x8 bv0 = *(const bf16x8*)(vp);
      bf16x8 bv1 = *(const bf16x8*)(vp + 32);
      acc[n] = MFMA(pa0, bv0, acc[n], 0, 0, 0);
      acc[n] = MFMA(pa1, bv1, acc[n], 0, 0, 0);
    }
  }

  float inv = 1.0f / l_;   // lane's own q-row denominator
  #pragma unroll
  for (int j = 0; j < 4; j++) {
    float invj = __shfl(inv, lg * 4 + j);
    int row = qw0 + lg * 4 + j;
    if (row < S_) {
      #pragma unroll
      for (int n = 0; n < 4; n++) {
        float v = acc[n][j] * invj;
        Ctx[((size_t)(b * S_ + row)) * D_ + h * HD_ + n * 16 + l16] = f2bf(v);
      }
    }
  }
}

extern "C" void kernel_launch(void* const* d_in, const int* in_sizes, int n_in,
                              void* d_out, int out_size, void* d_ws, size_t ws_size,
                              hipStream_t stream) {
  const float* hs   = (const float*)d_in[0];
  const float* mask = (const float*)d_in[1];
  const float* q_w  = (const float*)d_in[2];
  const float* q_b  = (const float*)d_in[3];
  const float* k_w  = (const float*)d_in[4];
  const float* v_w  = (const float*)d_in[5];
  const float* v_b  = (const float*)d_in[6];
  const float* o_w  = (const float*)d_in[7];
  const float* o_b  = (const float*)d_in[8];
  float* out = (float*)d_out;

  char* w = (char*)d_ws;
  const size_t XD = (size_t)M_ * D_;
  const size_t WD = (size_t)D_ * D_;
  u16* Xb  = (u16*)(w);                 w += XD * 2;
  u16* Wtq = (u16*)(w);                 w += WD * 2;
  u16* Wtk = (u16*)(w);                 w += WD * 2;
  u16* Wtv = (u16*)(w);                 w += WD * 2;
  u16* Wto = (u16*)(w);                 w += WD * 2;
  u16* Qb  = (u16*)(w);                 w += XD * 2;
  u16* Kb  = (u16*)(w);                 w += XD * 2;
  u16* Vb  = (u16*)(w);                 w += XD * 2;
  u16* Vt  = (u16*)(w);                 w += (size_t)B_ * H_ * HD_ * SPAD * 2;
  u16* Ctx = Xb;   // alias: Xb dead after V projection

  k_conv<<<dim3(3750), dim3(256), 0, stream>>>(hs, Xb);
  k_trans<<<dim3(40, 40), dim3(256), 0, stream>>>(q_w, Wtq);
  k_trans<<<dim3(40, 40), dim3(256), 0, stream>>>(k_w, Wtk);
  k_trans<<<dim3(40, 40), dim3(256), 0, stream>>>(v_w, Wtv);
  k_trans<<<dim3(40, 40), dim3(256), 0, stream>>>(o_w, Wto);

  dim3 gg(47, 10);
  k_gemm<0><<<gg, dim3(256), 0, stream>>>(Xb, Wtq, q_b, Qb);
  k_gemm<1><<<gg, dim3(256), 0, stream>>>(Xb, Wtk, nullptr, Kb);
  k_gemm<2><<<gg, dim3(256), 0, stream>>>(Xb, Wtv, v_b, Vb);
  k_vtrans<<<dim3(80, 12), dim3(256), 0, stream>>>(Vb, Vt);

  k_attn<<<dim3(24, 80), dim3(256), 0, stream>>>(Qb, Kb, Vt, mask, Ctx);

  k_gemm<3><<<gg, dim3(256), 0, stream>>>(Ctx, Wto, o_b, out);
}

// Round 4
// 307.711 us; speedup vs baseline: 3.4974x; 1.7835x over previous
//
#include <hip/hip_runtime.h>
#include <hip/hip_bf16.h>
#include <cstddef>

#define B_   4
#define S_   1500
#define D_   1280
#define H_   20
#define HD_  64
#define M_   (B_*S_)
#define SPAD 1536
#define BIGNEG (-1e30f)
#define LOG2E 1.44269504088896340736f
#define KVB  32
#define NT   47   // ceil(1500/32)

typedef short bf16x8 __attribute__((ext_vector_type(8)));
typedef float f32x4 __attribute__((ext_vector_type(4)));
typedef unsigned short u16;
typedef u16 u16x8 __attribute__((ext_vector_type(8)));

#define MFMA __builtin_amdgcn_mfma_f32_16x16x32_bf16

__device__ __forceinline__ u16 f2bf(float f) {
  union { float f; unsigned u; } x; x.f = f;
  unsigned r = (x.u + 0x7fffu + ((x.u >> 16) & 1u)) >> 16;
  return (u16)r;
}

__device__ __forceinline__ unsigned cvtpk(float a, float b) {
  unsigned r;
  asm volatile("v_cvt_pk_bf16_f32 %0, %1, %2" : "=v"(r) : "v"(a), "v"(b));
  return r;
}

__device__ __forceinline__ void gl_lds16(const u16* g, u16* l) {
  typedef __attribute__((address_space(1))) const unsigned GU;
  typedef __attribute__((address_space(3))) unsigned LU;
  __builtin_amdgcn_global_load_lds((GU*)g, (LU*)l, 16, 0, 0);
}

// ---- fp32 -> bf16 bulk convert (8 elems/thread) ----
__global__ __launch_bounds__(256) void k_conv(const float* __restrict__ X, u16* __restrict__ Y) {
  size_t i = (size_t)blockIdx.x * 256 + threadIdx.x;
  const float4* p = (const float4*)(X + i * 8);
  float4 a = p[0], b = p[1];
  u16x8 v;
  v[0]=f2bf(a.x); v[1]=f2bf(a.y); v[2]=f2bf(a.z); v[3]=f2bf(a.w);
  v[4]=f2bf(b.x); v[5]=f2bf(b.y); v[6]=f2bf(b.z); v[7]=f2bf(b.w);
  *(u16x8*)(Y + i * 8) = v;
}

// ---- W[k][n] fp32 -> Wt[n][k] bf16 transpose ----
__global__ __launch_bounds__(256) void k_trans(const float* __restrict__ W, u16* __restrict__ Wt) {
  __shared__ float t[32][33];
  int n0 = blockIdx.x * 32, k0 = blockIdx.y * 32;
  int tx = threadIdx.x & 31, ty = threadIdx.x >> 5;
  #pragma unroll
  for (int i = ty; i < 32; i += 8) t[i][tx] = W[(size_t)(k0 + i) * D_ + n0 + tx];
  __syncthreads();
  #pragma unroll
  for (int i = ty; i < 32; i += 8) Wt[(size_t)(n0 + i) * D_ + k0 + tx] = f2bf(t[tx][i]);
}

// ---- Vb[M][D] bf16 -> Vt[bh][d][SPAD] bf16 (per-head transpose) ----
__global__ __launch_bounds__(256) void k_vtrans(const u16* __restrict__ Vb, u16* __restrict__ Vt) {
  __shared__ u16 t[128][72];
  int bh = blockIdx.x, b = bh / H_, h = bh % H_;
  int s0 = blockIdx.y * 128;
  int tid = threadIdx.x;
  #pragma unroll
  for (int r = 0; r < 4; r++) {
    int sl = r * 32 + (tid >> 3);
    int s = s0 + sl; if (s > S_ - 1) s = S_ - 1;
    bf16x8 v = *(const bf16x8*)(Vb + ((size_t)(b * S_ + s)) * D_ + h * HD_ + (tid & 7) * 8);
    *(bf16x8*)&t[sl][(tid & 7) * 8] = v;
  }
  __syncthreads();
  #pragma unroll
  for (int r = 0; r < 4; r++) {
    int d = r * 16 + (tid >> 4);
    int ss = (tid & 15) * 8;
    u16x8 o;
    #pragma unroll
    for (int q = 0; q < 8; q++) o[q] = t[ss + q][d];
    *(u16x8*)(Vt + ((size_t)bh * HD_ + d) * SPAD + s0 + ss) = o;
  }
}

// ---- GEMM: C[M,1280] = A[M,1280] @ Wt^T + bias ; 128x128 tile, BK=64 ----
template <int MODE>
__global__ __launch_bounds__(256) void k_gemm(const u16* __restrict__ A,
                                              const u16* __restrict__ Wt,
                                              const float* __restrict__ bias,
                                              void* __restrict__ outp) {
  __shared__ u16 As[128 * 64];
  __shared__ u16 Bs[128 * 64];
  int tid = threadIdx.x;
  int lane = tid & 63;
  int wv = tid >> 6;
  int l16 = lane & 15, lg = lane >> 4;
  int wr = wv >> 1, wc = wv & 1;
  int m0 = blockIdx.x * 128, n0 = blockIdx.y * 128;

  int srow = tid >> 3, scol = tid & 7;
  int wcol8 = ((scol ^ (srow & 7))) * 8;

  f32x4 acc[4][4] = {};

  for (int k0 = 0; k0 < D_; k0 += 64) {
    bf16x8 ta[4], tb[4];
    #pragma unroll
    for (int c = 0; c < 4; c++) {
      int row = srow + c * 32;
      int ar = m0 + row; if (ar > M_ - 1) ar = M_ - 1;
      ta[c] = *(const bf16x8*)(A  + (size_t)ar * D_ + k0 + scol * 8);
      tb[c] = *(const bf16x8*)(Wt + (size_t)(n0 + row) * D_ + k0 + scol * 8);
    }
    __syncthreads();
    #pragma unroll
    for (int c = 0; c < 4; c++) {
      int row = srow + c * 32;
      *(bf16x8*)&As[row * 64 + wcol8] = ta[c];
      *(bf16x8*)&Bs[row * 64 + wcol8] = tb[c];
    }
    __syncthreads();
    #pragma unroll
    for (int kk = 0; kk < 2; kk++) {
      int pcol = ((kk * 4 + lg) ^ (l16 & 7)) * 8;
      bf16x8 af[4], bf[4];
      #pragma unroll
      for (int m = 0; m < 4; m++)
        af[m] = *(const bf16x8*)&As[(wr * 64 + m * 16 + l16) * 64 + pcol];
      #pragma unroll
      for (int n = 0; n < 4; n++)
        bf[n] = *(const bf16x8*)&Bs[(wc * 64 + n * 16 + l16) * 64 + pcol];
      __builtin_amdgcn_s_setprio(1);
      #pragma unroll
      for (int m = 0; m < 4; m++)
        #pragma unroll
        for (int n = 0; n < 4; n++)
          acc[m][n] = MFMA(af[m], bf[n], acc[m][n], 0, 0, 0);
      __builtin_amdgcn_s_setprio(0);
    }
  }

  #pragma unroll
  for (int m = 0; m < 4; m++) {
    int row0 = m0 + wr * 64 + m * 16 + lg * 4;
    #pragma unroll
    for (int n = 0; n < 4; n++) {
      int col = n0 + wc * 64 + n * 16 + l16;
      float bv = (MODE == 1) ? 0.0f : bias[col];
      #pragma unroll
      for (int j = 0; j < 4; j++) {
        int row = row0 + j;
        if (row < M_) {
          float v = acc[m][n][j] + bv;
          if (MODE == 0)      ((u16*)outp)[(size_t)row * D_ + col] = f2bf(v * (0.125f * LOG2E));
          else if (MODE == 3) ((float*)outp)[(size_t)row * D_ + col] = v;
          else                ((u16*)outp)[(size_t)row * D_ + col] = f2bf(v);
        }
      }
    }
  }
}

// ---- Flash attention: LDS-shared K/V, double-buffered, counted-vmcnt pipeline ----
// grid (24 q-tiles, 80 b*h), 4 waves x 16 q-rows, KVB=32
__global__ __launch_bounds__(256) void k_attn(const u16* __restrict__ Qb,
                                              const u16* __restrict__ Kb,
                                              const u16* __restrict__ Vt,
                                              const float* __restrict__ mask,
                                              u16* __restrict__ Ctx) {
  __shared__ u16 Kl[2][32 * 64];   // [key][d]  rows 128B, slot-XOR (r&7)
  __shared__ u16 Vl[2][64 * 32];   // [d][key]  rows 64B,  slot-XOR (r&3)
  __shared__ u16 pl[4][16 * 40];   // per-wave P relayout, 80B rows

  int tid = threadIdx.x;
  int lane = tid & 63, wv = tid >> 6;
  int l16 = lane & 15, lg = lane >> 4;
  int bh = blockIdx.y, b = bh / H_, h = bh % H_;
  int qw0 = blockIdx.x * 64 + wv * 16;

  int qr = qw0 + l16; if (qr > S_ - 1) qr = S_ - 1;
  const u16* qp = Qb + ((size_t)(b * S_ + qr)) * D_ + h * HD_ + lg * 8;
  bf16x8 aq0 = *(const bf16x8*)(qp);
  bf16x8 aq1 = *(const bf16x8*)(qp + 32);
  const float* mrow = mask + (size_t)b * S_ * S_ + (size_t)qr * S_;

  // staging lane constants (inverse-swizzled global sources)
  int krow = wv * 8 + (lane >> 3);                               // local K row
  int ksw  = (((lane & 7) * 16) ^ ((krow & 7) << 4)) >> 1;       // elem off in d-slice
  const u16* ksrc0 = Kb + (size_t)b * S_ * D_ + h * HD_ + ksw;   // + key*D_
  int vrow = wv * 16 + (lane >> 2);                              // V d-row
  int vsw  = ((((lane & 3) * 16) ^ ((vrow & 3) << 4)) >> 1);     // key-elem off
  const u16* vsrc0 = Vt + ((size_t)bh * HD_ + vrow) * SPAD + vsw; // + k0

  float m_ = BIGNEG, l_ = 0.0f;
  f32x4 acc[4] = {};
  const f32x4 zf = {0, 0, 0, 0};

#define STAGE(k0s, bufb) do {                                         \
    int key_ = (k0s) + krow; if (key_ > S_ - 1) key_ = S_ - 1;        \
    u16* kd_ = (bufb) ? &Kl[1][0] : &Kl[0][0];                        \
    u16* vd_ = (bufb) ? &Vl[1][0] : &Vl[0][0];                        \
    gl_lds16(ksrc0 + (size_t)key_ * D_, kd_ + wv * 512);              \
    gl_lds16(vsrc0 + (k0s), vd_ + wv * 512);                          \
  } while (0)

#define COMPUTE(curb, LASTV) do {                                     \
    const u16* KlC = (curb) ? &Kl[1][0] : &Kl[0][0];                  \
    const u16* VlC = (curb) ? &Vl[1][0] : &Vl[0][0];                  \
    f32x4 s[2];                                                       \
    _Pragma("unroll")                                                 \
    for (int sub = 0; sub < 2; sub++) {                               \
      const u16* kb = KlC + (sub * 16 + l16) * 64;                    \
      bf16x8 kf0 = *(const bf16x8*)(kb + ((lg    ) ^ (l16 & 7)) * 8); \
      bf16x8 kf1 = *(const bf16x8*)(kb + ((4 + lg) ^ (l16 & 7)) * 8); \
      s[sub] = MFMA(kf0, aq0, zf, 0, 0, 0);                           \
      s[sub] = MFMA(kf1, aq1, s[sub], 0, 0, 0);                       \
    }                                                                 \
    s[0][0] = fmaf(mv0.x, LOG2E, s[0][0]);                            \
    s[0][1] = fmaf(mv0.y, LOG2E, s[0][1]);                            \
    s[0][2] = fmaf(mv0.z, LOG2E, s[0][2]);                            \
    s[0][3] = fmaf(mv0.w, LOG2E, s[0][3]);                            \
    s[1][0] = fmaf(mv1.x, LOG2E, s[1][0]);                            \
    s[1][1] = fmaf(mv1.y, LOG2E, s[1][1]);                            \
    s[1][2] = fmaf(mv1.z, LOG2E, s[1][2]);                            \
    s[1][3] = fmaf(mv1.w, LOG2E, s[1][3]);                            \
    if (LASTV && lg == 3) {                                           \
      s[1][0] = BIGNEG; s[1][1] = BIGNEG;                             \
      s[1][2] = BIGNEG; s[1][3] = BIGNEG;                             \
    }                                                                 \
    float t0 = fmaxf(fmaxf(s[0][0], s[0][1]), fmaxf(s[0][2], s[0][3]));\
    float t1 = fmaxf(fmaxf(s[1][0], s[1][1]), fmaxf(s[1][2], s[1][3]));\
    float rmax = fmaxf(t0, t1);                                       \
    rmax = fmaxf(rmax, __shfl_xor(rmax, 16));                         \
    rmax = fmaxf(rmax, __shfl_xor(rmax, 32));                         \
    float mn = fmaxf(m_, rmax);                                       \
    if (!__all(mn - m_ <= 8.0f)) {                                    \
      float c = __builtin_amdgcn_exp2f(m_ - mn);                      \
      m_ = mn; l_ *= c;                                               \
      _Pragma("unroll")                                               \
      for (int j = 0; j < 4; j++) {                                   \
        float cj = __shfl(c, lg * 4 + j);                             \
        acc[0][j] *= cj; acc[1][j] *= cj;                             \
        acc[2][j] *= cj; acc[3][j] *= cj;                             \
      }                                                               \
    }                                                                 \
    _Pragma("unroll")                                                 \
    for (int sub = 0; sub < 2; sub++)                                 \
      _Pragma("unroll")                                               \
      for (int j = 0; j < 4; j++)                                     \
        s[sub][j] = __builtin_amdgcn_exp2f(s[sub][j] - m_);           \
    float a0 = (s[0][0] + s[0][1]) + (s[0][2] + s[0][3]);             \
    float a1 = (s[1][0] + s[1][1]) + (s[1][2] + s[1][3]);             \
    float rs = a0 + a1;                                               \
    rs += __shfl_xor(rs, 16);                                         \
    rs += __shfl_xor(rs, 32);                                         \
    l_ += rs;                                                         \
    uint2 w0, w1;                                                     \
    w0.x = cvtpk(s[0][0], s[0][1]); w0.y = cvtpk(s[0][2], s[0][3]);   \
    w1.x = cvtpk(s[1][0], s[1][1]); w1.y = cvtpk(s[1][2], s[1][3]);   \
    *(uint2*)&pl[wv][l16 * 40 + lg * 4]      = w0;                    \
    *(uint2*)&pl[wv][l16 * 40 + 16 + lg * 4] = w1;                    \
    bf16x8 pa = *(const bf16x8*)&pl[wv][l16 * 40 + lg * 8];           \
    _Pragma("unroll")                                                 \
    for (int n = 0; n < 4; n++) {                                     \
      int row = n * 16 + l16;                                         \
      bf16x8 bv = *(const bf16x8*)(VlC + row * 32 + ((lg ^ (l16 & 3)) * 8)); \
      acc[n] = MFMA(pa, bv, acc[n], 0, 0, 0);                         \
    }                                                                 \
  } while (0)

  STAGE(0, 0);

  for (int t = 0; t < NT - 1; t++) {
    int k0 = t * KVB;
    float4 mv0 = *(const float4*)(mrow + k0 + lg * 4);
    float4 mv1 = *(const float4*)(mrow + k0 + 16 + lg * 4);
    __builtin_amdgcn_s_barrier();
    asm volatile("" ::: "memory");
    STAGE(k0 + KVB, (t + 1) & 1);
    asm volatile("s_waitcnt vmcnt(2)" ::: "memory");
    __builtin_amdgcn_s_barrier();
    asm volatile("" ::: "memory");
    COMPUTE(t & 1, false);
  }
  {
    const int k0 = (NT - 1) * KVB;
    float4 mv0 = *(const float4*)(mrow + k0 + lg * 4);
    int mc1 = k0 + 16 + lg * 4; if (mc1 > S_ - 4) mc1 = S_ - 4;
    float4 mv1 = *(const float4*)(mrow + mc1);
    __builtin_amdgcn_s_barrier();
    asm volatile("s_waitcnt vmcnt(0)" ::: "memory");
    __builtin_amdgcn_s_barrier();
    asm volatile("" ::: "memory");
    COMPUTE((NT - 1) & 1, true);
  }

  float inv = 1.0f / l_;
  #pragma unroll
  for (int j = 0; j < 4; j++) {
    float invj = __shfl(inv, lg * 4 + j);
    int row = qw0 + lg * 4 + j;
    if (row < S_) {
      #pragma unroll
      for (int n = 0; n < 4; n++) {
        float v = acc[n][j] * invj;
        Ctx[((size_t)(b * S_ + row)) * D_ + h * HD_ + n * 16 + l16] = f2bf(v);
      }
    }
  }
#undef STAGE
#undef COMPUTE
}

extern "C" void kernel_launch(void* const* d_in, const int* in_sizes, int n_in,
                              void* d_out, int out_size, void* d_ws, size_t ws_size,
                              hipStream_t stream) {
  const float* hs   = (const float*)d_in[0];
  const float* mask = (const float*)d_in[1];
  const float* q_w  = (const float*)d_in[2];
  const float* q_b  = (const float*)d_in[3];
  const float* k_w  = (const float*)d_in[4];
  const float* v_w  = (const float*)d_in[5];
  const float* v_b  = (const float*)d_in[6];
  const float* o_w  = (const float*)d_in[7];
  const float* o_b  = (const float*)d_in[8];
  float* out = (float*)d_out;

  char* w = (char*)d_ws;
  const size_t XD = (size_t)M_ * D_;
  const size_t WD = (size_t)D_ * D_;
  u16* Xb  = (u16*)(w);                 w += XD * 2;
  u16* Wtq = (u16*)(w);                 w += WD * 2;
  u16* Wtk = (u16*)(w);                 w += WD * 2;
  u16* Wtv = (u16*)(w);                 w += WD * 2;
  u16* Wto = (u16*)(w);                 w += WD * 2;
  u16* Qb  = (u16*)(w);                 w += XD * 2;
  u16* Kb  = (u16*)(w);                 w += XD * 2;
  u16* Vb  = (u16*)(w);                 w += XD * 2;
  u16* Vt  = (u16*)(w);                 w += (size_t)B_ * H_ * HD_ * SPAD * 2;
  u16* Ctx = Xb;   // alias: Xb dead after V projection

  k_conv<<<dim3(3750), dim3(256), 0, stream>>>(hs, Xb);
  k_trans<<<dim3(40, 40), dim3(256), 0, stream>>>(q_w, Wtq);
  k_trans<<<dim3(40, 40), dim3(256), 0, stream>>>(k_w, Wtk);
  k_trans<<<dim3(40, 40), dim3(256), 0, stream>>>(v_w, Wtv);
  k_trans<<<dim3(40, 40), dim3(256), 0, stream>>>(o_w, Wto);

  dim3 gg(47, 10);
  k_gemm<0><<<gg, dim3(256), 0, stream>>>(Xb, Wtq, q_b, Qb);
  k_gemm<1><<<gg, dim3(256), 0, stream>>>(Xb, Wtk, nullptr, Kb);
  k_gemm<2><<<gg, dim3(256), 0, stream>>>(Xb, Wtv, v_b, Vb);
  k_vtrans<<<dim3(80, 12), dim3(256), 0, stream>>>(Vb, Vt);

  k_attn<<<dim3(24, 80), dim3(256), 0, stream>>>(Qb, Kb, Vt, mask, Ctx);

  k_gemm<3><<<gg, dim3(256), 0, stream>>>(Ctx, Wto, o_b, out);
}

// Round 5
// 292.349 us; speedup vs baseline: 3.6811x; 1.0525x over previous
//
#include <hip/hip_runtime.h>
#include <hip/hip_bf16.h>
#include <cstddef>

#define B_   4
#define S_   1500
#define D_   1280
#define H_   20
#define HD_  64
#define M_   (B_*S_)
#define SPAD 1536
#define BIGNEG (-1e30f)
#define LOG2E 1.44269504088896340736f
#define KVB  64
#define NTA  24   // ceil(1500/64)

typedef short bf16x8 __attribute__((ext_vector_type(8)));
typedef float f32x4 __attribute__((ext_vector_type(4)));
typedef unsigned short u16;
typedef u16 u16x8 __attribute__((ext_vector_type(8)));

#define MFMA __builtin_amdgcn_mfma_f32_16x16x32_bf16

__device__ __forceinline__ u16 f2bf(float f) {
  union { float f; unsigned u; } x; x.f = f;
  unsigned r = (x.u + 0x7fffu + ((x.u >> 16) & 1u)) >> 16;
  return (u16)r;
}

__device__ __forceinline__ unsigned cvtpk(float a, float b) {
  unsigned r;
  asm volatile("v_cvt_pk_bf16_f32 %0, %1, %2" : "=v"(r) : "v"(a), "v"(b));
  return r;
}

__device__ __forceinline__ void gl_lds16(const u16* g, u16* l) {
  typedef __attribute__((address_space(1))) const unsigned GU;
  typedef __attribute__((address_space(3))) unsigned LU;
  __builtin_amdgcn_global_load_lds((GU*)g, (LU*)l, 16, 0, 0);
}

// ---- fp32 -> bf16 bulk convert (8 elems/thread) ----
__global__ __launch_bounds__(256) void k_conv(const float* __restrict__ X, u16* __restrict__ Y) {
  size_t i = (size_t)blockIdx.x * 256 + threadIdx.x;
  const float4* p = (const float4*)(X + i * 8);
  float4 a = p[0], b = p[1];
  u16x8 v;
  v[0]=f2bf(a.x); v[1]=f2bf(a.y); v[2]=f2bf(a.z); v[3]=f2bf(a.w);
  v[4]=f2bf(b.x); v[5]=f2bf(b.y); v[6]=f2bf(b.z); v[7]=f2bf(b.w);
  *(u16x8*)(Y + i * 8) = v;
}

// ---- W[k][n] fp32 -> Wt[n][k] bf16 transpose ----
__global__ __launch_bounds__(256) void k_trans(const float* __restrict__ W, u16* __restrict__ Wt) {
  __shared__ float t[32][33];
  int n0 = blockIdx.x * 32, k0 = blockIdx.y * 32;
  int tx = threadIdx.x & 31, ty = threadIdx.x >> 5;
  #pragma unroll
  for (int i = ty; i < 32; i += 8) t[i][tx] = W[(size_t)(k0 + i) * D_ + n0 + tx];
  __syncthreads();
  #pragma unroll
  for (int i = ty; i < 32; i += 8) Wt[(size_t)(n0 + i) * D_ + k0 + tx] = f2bf(t[tx][i]);
}

// ---- Vb[M][D] bf16 -> Vt[bh][d][SPAD] bf16 (per-head transpose) ----
__global__ __launch_bounds__(256) void k_vtrans(const u16* __restrict__ Vb, u16* __restrict__ Vt) {
  __shared__ u16 t[128][72];
  int bh = blockIdx.x, b = bh / H_, h = bh % H_;
  int s0 = blockIdx.y * 128;
  int tid = threadIdx.x;
  #pragma unroll
  for (int r = 0; r < 4; r++) {
    int sl = r * 32 + (tid >> 3);
    int s = s0 + sl; if (s > S_ - 1) s = S_ - 1;
    bf16x8 v = *(const bf16x8*)(Vb + ((size_t)(b * S_ + s)) * D_ + h * HD_ + (tid & 7) * 8);
    *(bf16x8*)&t[sl][(tid & 7) * 8] = v;
  }
  __syncthreads();
  #pragma unroll
  for (int r = 0; r < 4; r++) {
    int d = r * 16 + (tid >> 4);
    int ss = (tid & 15) * 8;
    u16x8 o;
    #pragma unroll
    for (int q = 0; q < 8; q++) o[q] = t[ss + q][d];
    *(u16x8*)(Vt + ((size_t)bh * HD_ + d) * SPAD + s0 + ss) = o;
  }
}

// ---- GEMM: C[M,1280] = A[M,1280] @ Wt^T + bias ; 128x128 tile, BK=64, sw-pipelined ----
template <int MODE>
__global__ __launch_bounds__(256) void k_gemm(const u16* __restrict__ A,
                                              const u16* __restrict__ Wt,
                                              const float* __restrict__ bias,
                                              void* __restrict__ outp) {
  __shared__ u16 As[128 * 64];
  __shared__ u16 Bs[128 * 64];
  int tid = threadIdx.x;
  int lane = tid & 63;
  int wv = tid >> 6;
  int l16 = lane & 15, lg = lane >> 4;
  int wr = wv >> 1, wc = wv & 1;
  int m0 = blockIdx.x * 128, n0 = blockIdx.y * 128;

  int srow = tid >> 3, scol = tid & 7;
  int wcol8 = ((scol ^ (srow & 7))) * 8;

  f32x4 acc[4][4] = {};
  bf16x8 ta[4], tb[4];

#define LOADT(tt) do {                                                    \
    int kk0 = (tt) * 64;                                                  \
    _Pragma("unroll")                                                     \
    for (int c = 0; c < 4; c++) {                                         \
      int row = srow + c * 32;                                            \
      int ar = m0 + row; if (ar > M_ - 1) ar = M_ - 1;                    \
      ta[c] = *(const bf16x8*)(A  + (size_t)ar * D_ + kk0 + scol * 8);    \
      tb[c] = *(const bf16x8*)(Wt + (size_t)(n0 + row) * D_ + kk0 + scol * 8); \
    }                                                                     \
  } while (0)

  LOADT(0);
  for (int t = 0; t < 20; t++) {
    __syncthreads();
    #pragma unroll
    for (int c = 0; c < 4; c++) {
      int row = srow + c * 32;
      *(bf16x8*)&As[row * 64 + wcol8] = ta[c];
      *(bf16x8*)&Bs[row * 64 + wcol8] = tb[c];
    }
    if (t < 19) LOADT(t + 1);   // latency hides under compute below
    __syncthreads();
    #pragma unroll
    for (int kk = 0; kk < 2; kk++) {
      int pcol = ((kk * 4 + lg) ^ (l16 & 7)) * 8;
      bf16x8 af[4], bf[4];
      #pragma unroll
      for (int m = 0; m < 4; m++)
        af[m] = *(const bf16x8*)&As[(wr * 64 + m * 16 + l16) * 64 + pcol];
      #pragma unroll
      for (int n = 0; n < 4; n++)
        bf[n] = *(const bf16x8*)&Bs[(wc * 64 + n * 16 + l16) * 64 + pcol];
      __builtin_amdgcn_s_setprio(1);
      #pragma unroll
      for (int m = 0; m < 4; m++)
        #pragma unroll
        for (int n = 0; n < 4; n++)
          acc[m][n] = MFMA(af[m], bf[n], acc[m][n], 0, 0, 0);
      __builtin_amdgcn_s_setprio(0);
    }
  }
#undef LOADT

  #pragma unroll
  for (int m = 0; m < 4; m++) {
    int row0 = m0 + wr * 64 + m * 16 + lg * 4;
    #pragma unroll
    for (int n = 0; n < 4; n++) {
      int col = n0 + wc * 64 + n * 16 + l16;
      float bv = (MODE == 1) ? 0.0f : bias[col];
      #pragma unroll
      for (int j = 0; j < 4; j++) {
        int row = row0 + j;
        if (row < M_) {
          float v = acc[m][n][j] + bv;
          if (MODE == 0)      ((u16*)outp)[(size_t)row * D_ + col] = f2bf(v * (0.125f * LOG2E));
          else if (MODE == 3) ((float*)outp)[(size_t)row * D_ + col] = v;
          else                ((u16*)outp)[(size_t)row * D_ + col] = f2bf(v);
        }
      }
    }
  }
}

// ---- Flash attention: KVB=64, LDS-shared K/V double-buffered, counted vmcnt ----
// grid (24 q-tiles, 80 b*h), 4 waves x 16 q-rows
__global__ __launch_bounds__(256) void k_attn(const u16* __restrict__ Qb,
                                              const u16* __restrict__ Kb,
                                              const u16* __restrict__ Vt,
                                              const float* __restrict__ mask,
                                              u16* __restrict__ Ctx) {
  __shared__ u16 Kl[2][64 * 64];   // [key][d]   128B rows, slot-XOR (r&7)
  __shared__ u16 Vl[2][64 * 64];   // [d][key]   128B rows, slot-XOR (r&7)
  __shared__ u16 pl[4][16 * 72];   // per-wave P relayout, 144B rows

  int tid = threadIdx.x;
  int lane = tid & 63, wv = tid >> 6;
  int l16 = lane & 15, lg = lane >> 4;
  int bh = blockIdx.y, b = bh / H_, h = bh % H_;
  int qw0 = blockIdx.x * 64 + wv * 16;

  int qr = qw0 + l16; if (qr > S_ - 1) qr = S_ - 1;
  const u16* qp = Qb + ((size_t)(b * S_ + qr)) * D_ + h * HD_ + lg * 8;
  bf16x8 aq0 = *(const bf16x8*)(qp);
  bf16x8 aq1 = *(const bf16x8*)(qp + 32);
  const float* mrow = mask + (size_t)b * S_ * S_ + (size_t)qr * S_;

  // staging constants: dest rows wv*16 + i*8 + (lane>>3); row&7 == lane>>3
  int sr0 = wv * 16 + (lane >> 3);          // i=0 row
  int csw = ((lane & 7) ^ (lane >> 3)) * 8; // inverse-swizzled source elem offset
  const u16* ksrc = Kb + (size_t)b * S_ * D_ + h * HD_ + csw;       // + key*D_
  const u16* vsrc0 = Vt + ((size_t)bh * HD_ + sr0) * SPAD + csw;     // + k0
  const u16* vsrc1 = vsrc0 + 8 * SPAD;

  float m_ = BIGNEG, l_ = 0.0f;
  f32x4 acc[4] = {};
  const f32x4 zf = {0, 0, 0, 0};
  float4 mvs[4];

#define STAGE(k0s, bufb) do {                                          \
    int key0_ = (k0s) + sr0;     if (key0_ > S_ - 1) key0_ = S_ - 1;   \
    int key1_ = key0_ + 8;       if (key1_ > S_ - 1) key1_ = S_ - 1;   \
    u16* kd_ = &Kl[bufb][0] + wv * 1024;                               \
    u16* vd_ = &Vl[bufb][0] + wv * 1024;                               \
    gl_lds16(ksrc + (size_t)key0_ * D_, kd_);                          \
    gl_lds16(ksrc + (size_t)key1_ * D_, kd_ + 512);                    \
    gl_lds16(vsrc0 + (k0s), vd_);                                      \
    gl_lds16(vsrc1 + (k0s), vd_ + 512);                                \
  } while (0)

#define COMPUTE(curb, LASTV) do {                                      \
    const u16* KlC = &Kl[curb][0];                                     \
    const u16* VlC = &Vl[curb][0];                                     \
    f32x4 s[4];                                                        \
    __builtin_amdgcn_s_setprio(1);                                     \
    _Pragma("unroll")                                                  \
    for (int sub = 0; sub < 4; sub++) {                                \
      const u16* kb = KlC + (sub * 16 + l16) * 64;                     \
      bf16x8 kf0 = *(const bf16x8*)(kb + ((lg     ^ (l16 & 7)) * 8));  \
      bf16x8 kf1 = *(const bf16x8*)(kb + (((4+lg) ^ (l16 & 7)) * 8));  \
      s[sub] = MFMA(kf0, aq0, zf, 0, 0, 0);                            \
      s[sub] = MFMA(kf1, aq1, s[sub], 0, 0, 0);                        \
    }                                                                  \
    __builtin_amdgcn_s_setprio(0);                                     \
    _Pragma("unroll")                                                  \
    for (int sub = 0; sub < 4; sub++) {                                \
      s[sub][0] = fmaf(mvs[sub].x, LOG2E, s[sub][0]);                  \
      s[sub][1] = fmaf(mvs[sub].y, LOG2E, s[sub][1]);                  \
      s[sub][2] = fmaf(mvs[sub].z, LOG2E, s[sub][2]);                  \
      s[sub][3] = fmaf(mvs[sub].w, LOG2E, s[sub][3]);                  \
    }                                                                  \
    if (LASTV) {                                                       \
      _Pragma("unroll")                                                \
      for (int sub = 0; sub < 4; sub++) {                              \
        int kb_ = 1472 + sub * 16 + lg * 4;                            \
        _Pragma("unroll")                                              \
        for (int j = 0; j < 4; j++)                                    \
          if (kb_ + j >= S_) s[sub][j] = BIGNEG;                       \
      }                                                                \
    }                                                                  \
    float t0 = fmaxf(fmaxf(s[0][0], s[0][1]), fmaxf(s[0][2], s[0][3]));\
    float t1 = fmaxf(fmaxf(s[1][0], s[1][1]), fmaxf(s[1][2], s[1][3]));\
    float t2 = fmaxf(fmaxf(s[2][0], s[2][1]), fmaxf(s[2][2], s[2][3]));\
    float t3 = fmaxf(fmaxf(s[3][0], s[3][1]), fmaxf(s[3][2], s[3][3]));\
    float rmax = fmaxf(fmaxf(t0, t1), fmaxf(t2, t3));                  \
    rmax = fmaxf(rmax, __shfl_xor(rmax, 16));                          \
    rmax = fmaxf(rmax, __shfl_xor(rmax, 32));                          \
    float mn = fmaxf(m_, rmax);                                        \
    if (!__all(mn - m_ <= 8.0f)) {                                     \
      float c = __builtin_amdgcn_exp2f(m_ - mn);                       \
      m_ = mn; l_ *= c;                                                \
      _Pragma("unroll")                                                \
      for (int j = 0; j < 4; j++) {                                    \
        float cj = __shfl(c, lg * 4 + j);                              \
        acc[0][j] *= cj; acc[1][j] *= cj;                              \
        acc[2][j] *= cj; acc[3][j] *= cj;                              \
      }                                                                \
    }                                                                  \
    _Pragma("unroll")                                                  \
    for (int sub = 0; sub < 4; sub++)                                  \
      _Pragma("unroll")                                                \
      for (int j = 0; j < 4; j++)                                      \
        s[sub][j] = __builtin_amdgcn_exp2f(s[sub][j] - m_);            \
    float a0 = (s[0][0] + s[0][1]) + (s[0][2] + s[0][3]);              \
    float a1 = (s[1][0] + s[1][1]) + (s[1][2] + s[1][3]);              \
    float a2 = (s[2][0] + s[2][1]) + (s[2][2] + s[2][3]);              \
    float a3 = (s[3][0] + s[3][1]) + (s[3][2] + s[3][3]);              \
    float rs = (a0 + a1) + (a2 + a3);                                  \
    rs += __shfl_xor(rs, 16);                                          \
    rs += __shfl_xor(rs, 32);                                          \
    l_ += rs;                                                          \
    _Pragma("unroll")                                                  \
    for (int sub = 0; sub < 4; sub++) {                                \
      uint2 w;                                                         \
      w.x = cvtpk(s[sub][0], s[sub][1]);                               \
      w.y = cvtpk(s[sub][2], s[sub][3]);                               \
      *(uint2*)&pl[wv][l16 * 72 + sub * 16 + lg * 4] = w;              \
    }                                                                  \
    bf16x8 pa0 = *(const bf16x8*)&pl[wv][l16 * 72 + lg * 8];           \
    bf16x8 pa1 = *(const bf16x8*)&pl[wv][l16 * 72 + 32 + lg * 8];      \
    __builtin_amdgcn_s_setprio(1);                                     \
    _Pragma("unroll")                                                  \
    for (int n = 0; n < 4; n++) {                                      \
      const u16* vb = VlC + (n * 16 + l16) * 64;                       \
      bf16x8 bv0 = *(const bf16x8*)(vb + ((lg     ^ (l16 & 7)) * 8));  \
      bf16x8 bv1 = *(const bf16x8*)(vb + (((4+lg) ^ (l16 & 7)) * 8));  \
      acc[n] = MFMA(pa0, bv0, acc[n], 0, 0, 0);                        \
      acc[n] = MFMA(pa1, bv1, acc[n], 0, 0, 0);                        \
    }                                                                  \
    __builtin_amdgcn_s_setprio(0);                                     \
  } while (0)

  STAGE(0, 0);

  for (int t = 0; t < NTA - 1; t++) {
    int k0 = t * KVB;
    #pragma unroll
    for (int sub = 0; sub < 4; sub++)
      mvs[sub] = *(const float4*)(mrow + k0 + sub * 16 + lg * 4);
    __builtin_amdgcn_s_barrier();
    asm volatile("" ::: "memory");
    STAGE(k0 + KVB, (t + 1) & 1);
    asm volatile("s_waitcnt vmcnt(4)" ::: "memory");
    __builtin_amdgcn_s_barrier();
    asm volatile("" ::: "memory");
    COMPUTE(t & 1, false);
  }
  {
    const int k0 = (NTA - 1) * KVB;   // 1472, tail = 28 keys
    #pragma unroll
    for (int sub = 0; sub < 4; sub++) {
      int mc = k0 + sub * 16 + lg * 4; if (mc > S_ - 4) mc = S_ - 4;
      mvs[sub] = *(const float4*)(mrow + mc);
    }
    __builtin_amdgcn_s_barrier();
    asm volatile("s_waitcnt vmcnt(0)" ::: "memory");
    __builtin_amdgcn_s_barrier();
    asm volatile("" ::: "memory");
    COMPUTE((NTA - 1) & 1, true);
  }

  float inv = 1.0f / l_;
  #pragma unroll
  for (int j = 0; j < 4; j++) {
    float invj = __shfl(inv, lg * 4 + j);
    int row = qw0 + lg * 4 + j;
    if (row < S_) {
      #pragma unroll
      for (int n = 0; n < 4; n++) {
        float v = acc[n][j] * invj;
        Ctx[((size_t)(b * S_ + row)) * D_ + h * HD_ + n * 16 + l16] = f2bf(v);
      }
    }
  }
#undef STAGE
#undef COMPUTE
}

extern "C" void kernel_launch(void* const* d_in, const int* in_sizes, int n_in,
                              void* d_out, int out_size, void* d_ws, size_t ws_size,
                              hipStream_t stream) {
  const float* hs   = (const float*)d_in[0];
  const float* mask = (const float*)d_in[1];
  const float* q_w  = (const float*)d_in[2];
  const float* q_b  = (const float*)d_in[3];
  const float* k_w  = (const float*)d_in[4];
  const float* v_w  = (const float*)d_in[5];
  const float* v_b  = (const float*)d_in[6];
  const float* o_w  = (const float*)d_in[7];
  const float* o_b  = (const float*)d_in[8];
  float* out = (float*)d_out;

  char* w = (char*)d_ws;
  const size_t XD = (size_t)M_ * D_;
  const size_t WD = (size_t)D_ * D_;
  u16* Xb  = (u16*)(w);                 w += XD * 2;
  u16* Wtq = (u16*)(w);                 w += WD * 2;
  u16* Wtk = (u16*)(w);                 w += WD * 2;
  u16* Wtv = (u16*)(w);                 w += WD * 2;
  u16* Wto = (u16*)(w);                 w += WD * 2;
  u16* Qb  = (u16*)(w);                 w += XD * 2;
  u16* Kb  = (u16*)(w);                 w += XD * 2;
  u16* Vb  = (u16*)(w);                 w += XD * 2;
  u16* Vt  = (u16*)(w);                 w += (size_t)B_ * H_ * HD_ * SPAD * 2;
  u16* Ctx = Xb;   // alias: Xb dead after V projection

  k_conv<<<dim3(3750), dim3(256), 0, stream>>>(hs, Xb);
  k_trans<<<dim3(40, 40), dim3(256), 0, stream>>>(q_w, Wtq);
  k_trans<<<dim3(40, 40), dim3(256), 0, stream>>>(k_w, Wtk);
  k_trans<<<dim3(40, 40), dim3(256), 0, stream>>>(v_w, Wtv);
  k_trans<<<dim3(40, 40), dim3(256), 0, stream>>>(o_w, Wto);

  dim3 gg(47, 10);
  k_gemm<0><<<gg, dim3(256), 0, stream>>>(Xb, Wtq, q_b, Qb);
  k_gemm<1><<<gg, dim3(256), 0, stream>>>(Xb, Wtk, nullptr, Kb);
  k_gemm<2><<<gg, dim3(256), 0, stream>>>(Xb, Wtv, v_b, Vb);
  k_vtrans<<<dim3(80, 12), dim3(256), 0, stream>>>(Vb, Vt);

  k_attn<<<dim3(24, 80), dim3(256), 0, stream>>>(Qb, Kb, Vt, mask, Ctx);

  k_gemm<3><<<gg, dim3(256), 0, stream>>>(Ctx, Wto, o_b, out);
}

// Round 6
// 286.134 us; speedup vs baseline: 3.7611x; 1.0217x over previous
//
#include <hip/hip_runtime.h>
#include <hip/hip_bf16.h>
#include <cstddef>

#define B_   4
#define S_   1500
#define D_   1280
#define H_   20
#define HD_  64
#define M_   (B_*S_)
#define SPAD 1536
#define BIGNEG (-1e30f)
#define LOG2E 1.44269504088896340736f
#define KVB  64
#define NTA  24   // ceil(1500/64)

typedef short bf16x8 __attribute__((ext_vector_type(8)));
typedef float f32x4 __attribute__((ext_vector_type(4)));
typedef unsigned short u16;
typedef u16 u16x8 __attribute__((ext_vector_type(8)));
typedef unsigned int u32x4v __attribute__((ext_vector_type(4)));

#define MFMA __builtin_amdgcn_mfma_f32_16x16x32_bf16

__device__ __forceinline__ u16 f2bf(float f) {
  union { float f; unsigned u; } x; x.f = f;
  unsigned r = (x.u + 0x7fffu + ((x.u >> 16) & 1u)) >> 16;
  return (u16)r;
}

__device__ __forceinline__ unsigned cvtpk(float a, float b) {
  unsigned r;
  asm volatile("v_cvt_pk_bf16_f32 %0, %1, %2" : "=v"(r) : "v"(a), "v"(b));
  return r;
}

__device__ __forceinline__ void gl_lds16(const u16* g, u16* l) {
  typedef __attribute__((address_space(1))) const unsigned GU;
  typedef __attribute__((address_space(3))) unsigned LU;
  __builtin_amdgcn_global_load_lds((GU*)g, (LU*)l, 16, 0, 0);
}

// ---- fp32 -> bf16 bulk convert (8 elems/thread) ----
__global__ __launch_bounds__(256) void k_conv(const float* __restrict__ X, u16* __restrict__ Y) {
  size_t i = (size_t)blockIdx.x * 256 + threadIdx.x;
  const float4* p = (const float4*)(X + i * 8);
  float4 a = p[0], b = p[1];
  u16x8 v;
  v[0]=f2bf(a.x); v[1]=f2bf(a.y); v[2]=f2bf(a.z); v[3]=f2bf(a.w);
  v[4]=f2bf(b.x); v[5]=f2bf(b.y); v[6]=f2bf(b.z); v[7]=f2bf(b.w);
  *(u16x8*)(Y + i * 8) = v;
}

// ---- 4 weights W[k][n] fp32 -> Wt[n][k] bf16 transpose, z-selected ----
__global__ __launch_bounds__(256) void k_trans4(const float* __restrict__ qw,
                                                const float* __restrict__ kw,
                                                const float* __restrict__ vw,
                                                const float* __restrict__ ow,
                                                u16* __restrict__ Wt) {
  const float* W = (blockIdx.z == 0) ? qw : (blockIdx.z == 1) ? kw
                   : (blockIdx.z == 2) ? vw : ow;
  u16* dst = Wt + (size_t)blockIdx.z * D_ * D_;
  __shared__ float t[32][33];
  int n0 = blockIdx.x * 32, k0 = blockIdx.y * 32;
  int tx = threadIdx.x & 31, ty = threadIdx.x >> 5;
  #pragma unroll
  for (int i = ty; i < 32; i += 8) t[i][tx] = W[(size_t)(k0 + i) * D_ + n0 + tx];
  __syncthreads();
  #pragma unroll
  for (int i = ty; i < 32; i += 8) dst[(size_t)(n0 + i) * D_ + k0 + tx] = f2bf(t[tx][i]);
}

// ---- Vb[M][D] bf16 -> Vt[bh][d][SPAD] bf16 (per-head transpose) ----
__global__ __launch_bounds__(256) void k_vtrans(const u16* __restrict__ Vb, u16* __restrict__ Vt) {
  __shared__ u16 t[128][72];
  int bh = blockIdx.x, b = bh / H_, h = bh % H_;
  int s0 = blockIdx.y * 128;
  int tid = threadIdx.x;
  #pragma unroll
  for (int r = 0; r < 4; r++) {
    int sl = r * 32 + (tid >> 3);
    int s = s0 + sl; if (s > S_ - 1) s = S_ - 1;
    bf16x8 v = *(const bf16x8*)(Vb + ((size_t)(b * S_ + s)) * D_ + h * HD_ + (tid & 7) * 8);
    *(bf16x8*)&t[sl][(tid & 7) * 8] = v;
  }
  __syncthreads();
  #pragma unroll
  for (int r = 0; r < 4; r++) {
    int d = r * 16 + (tid >> 4);
    int ss = (tid & 15) * 8;
    u16x8 o;
    #pragma unroll
    for (int q = 0; q < 8; q++) o[q] = t[ss + q][d];
    *(u16x8*)(Vt + ((size_t)bh * HD_ + d) * SPAD + s0 + ss) = o;
  }
}

// ---- Fused QKV GEMM: [M,1280]@[1280,3840] ; 128x128 tile, BK=64, sw-pipelined ----
__global__ __launch_bounds__(256) void k_gemmqkv(const u16* __restrict__ A,
                                                 const u16* __restrict__ Wt,
                                                 const float* __restrict__ q_b,
                                                 const float* __restrict__ v_b,
                                                 u16* __restrict__ Qb) {
  __shared__ u16 As[128 * 64];
  __shared__ u16 Bs[128 * 64];
  int tid = threadIdx.x;
  int lane = tid & 63;
  int wv = tid >> 6;
  int l16 = lane & 15, lg = lane >> 4;
  int wr = wv >> 1, wc = wv & 1;
  int m0 = blockIdx.x * 128;
  int n0g = blockIdx.y * 128;                 // 0..3839
  int sel = blockIdx.y / 10;                  // 0=Q,1=K,2=V
  int nloc = n0g - sel * 1280;

  int srow = tid >> 3, scol = tid & 7;
  int wcol8 = ((scol ^ (srow & 7))) * 8;

  f32x4 acc[4][4] = {};
  bf16x8 ta[4], tb[4];

#define LOADT(tt) do {                                                    \
    int kk0 = (tt) * 64;                                                  \
    _Pragma("unroll")                                                     \
    for (int c = 0; c < 4; c++) {                                         \
      int row = srow + c * 32;                                            \
      int ar = m0 + row; if (ar > M_ - 1) ar = M_ - 1;                    \
      ta[c] = *(const bf16x8*)(A  + (size_t)ar * D_ + kk0 + scol * 8);    \
      tb[c] = *(const bf16x8*)(Wt + (size_t)(n0g + row) * D_ + kk0 + scol * 8); \
    }                                                                     \
  } while (0)

  LOADT(0);
  for (int t = 0; t < 20; t++) {
    __syncthreads();
    #pragma unroll
    for (int c = 0; c < 4; c++) {
      int row = srow + c * 32;
      *(bf16x8*)&As[row * 64 + wcol8] = ta[c];
      *(bf16x8*)&Bs[row * 64 + wcol8] = tb[c];
    }
    if (t < 19) LOADT(t + 1);
    __syncthreads();
    #pragma unroll
    for (int kk = 0; kk < 2; kk++) {
      int pcol = ((kk * 4 + lg) ^ (l16 & 7)) * 8;
      bf16x8 af[4], bf[4];
      #pragma unroll
      for (int m = 0; m < 4; m++)
        af[m] = *(const bf16x8*)&As[(wr * 64 + m * 16 + l16) * 64 + pcol];
      #pragma unroll
      for (int n = 0; n < 4; n++)
        bf[n] = *(const bf16x8*)&Bs[(wc * 64 + n * 16 + l16) * 64 + pcol];
      __builtin_amdgcn_s_setprio(1);
      #pragma unroll
      for (int m = 0; m < 4; m++)
        #pragma unroll
        for (int n = 0; n < 4; n++)
          acc[m][n] = MFMA(af[m], bf[n], acc[m][n], 0, 0, 0);
      __builtin_amdgcn_s_setprio(0);
    }
  }
#undef LOADT

  const float* bias = (sel == 0) ? q_b : v_b;    // unused for sel==1
  float scl = (sel == 0) ? (0.125f * LOG2E) : 1.0f;
  u16* outb = Qb + (size_t)sel * ((size_t)M_ * D_);

  #pragma unroll
  for (int m = 0; m < 4; m++) {
    int row0 = m0 + wr * 64 + m * 16 + lg * 4;
    #pragma unroll
    for (int n = 0; n < 4; n++) {
      int colL = nloc + wc * 64 + n * 16 + l16;
      float bv = (sel == 1) ? 0.0f : bias[colL];
      #pragma unroll
      for (int j = 0; j < 4; j++) {
        int row = row0 + j;
        if (row < M_) {
          float v = (acc[m][n][j] + bv) * scl;
          outb[(size_t)row * D_ + colL] = f2bf(v);
        }
      }
    }
  }
}

// ---- O GEMM: out[M,1280] fp32 = Ctx @ Wto + o_b ----
__global__ __launch_bounds__(256) void k_gemmo(const u16* __restrict__ A,
                                               const u16* __restrict__ Wt,
                                               const float* __restrict__ bias,
                                               float* __restrict__ outp) {
  __shared__ u16 As[128 * 64];
  __shared__ u16 Bs[128 * 64];
  int tid = threadIdx.x;
  int lane = tid & 63;
  int wv = tid >> 6;
  int l16 = lane & 15, lg = lane >> 4;
  int wr = wv >> 1, wc = wv & 1;
  int m0 = blockIdx.x * 128, n0 = blockIdx.y * 128;

  int srow = tid >> 3, scol = tid & 7;
  int wcol8 = ((scol ^ (srow & 7))) * 8;

  f32x4 acc[4][4] = {};
  bf16x8 ta[4], tb[4];

#define LOADT(tt) do {                                                    \
    int kk0 = (tt) * 64;                                                  \
    _Pragma("unroll")                                                     \
    for (int c = 0; c < 4; c++) {                                         \
      int row = srow + c * 32;                                            \
      int ar = m0 + row; if (ar > M_ - 1) ar = M_ - 1;                    \
      ta[c] = *(const bf16x8*)(A  + (size_t)ar * D_ + kk0 + scol * 8);    \
      tb[c] = *(const bf16x8*)(Wt + (size_t)(n0 + row) * D_ + kk0 + scol * 8); \
    }                                                                     \
  } while (0)

  LOADT(0);
  for (int t = 0; t < 20; t++) {
    __syncthreads();
    #pragma unroll
    for (int c = 0; c < 4; c++) {
      int row = srow + c * 32;
      *(bf16x8*)&As[row * 64 + wcol8] = ta[c];
      *(bf16x8*)&Bs[row * 64 + wcol8] = tb[c];
    }
    if (t < 19) LOADT(t + 1);
    __syncthreads();
    #pragma unroll
    for (int kk = 0; kk < 2; kk++) {
      int pcol = ((kk * 4 + lg) ^ (l16 & 7)) * 8;
      bf16x8 af[4], bf[4];
      #pragma unroll
      for (int m = 0; m < 4; m++)
        af[m] = *(const bf16x8*)&As[(wr * 64 + m * 16 + l16) * 64 + pcol];
      #pragma unroll
      for (int n = 0; n < 4; n++)
        bf[n] = *(const bf16x8*)&Bs[(wc * 64 + n * 16 + l16) * 64 + pcol];
      __builtin_amdgcn_s_setprio(1);
      #pragma unroll
      for (int m = 0; m < 4; m++)
        #pragma unroll
        for (int n = 0; n < 4; n++)
          acc[m][n] = MFMA(af[m], bf[n], acc[m][n], 0, 0, 0);
      __builtin_amdgcn_s_setprio(0);
    }
  }
#undef LOADT

  #pragma unroll
  for (int m = 0; m < 4; m++) {
    int row0 = m0 + wr * 64 + m * 16 + lg * 4;
    #pragma unroll
    for (int n = 0; n < 4; n++) {
      int col = n0 + wc * 64 + n * 16 + l16;
      float bv = bias[col];
      #pragma unroll
      for (int j = 0; j < 4; j++) {
        int row = row0 + j;
        if (row < M_) outp[(size_t)row * D_ + col] = acc[m][n][j] + bv;
      }
    }
  }
}

// ---- Flash attention: KVB=64, LDS K/V double-buffered, P fed to PV in-register ----
// grid (24 q-tiles, 80 b*h), 4 waves x 16 q-rows; LDS 32KB -> 5 blocks/CU
__global__ __launch_bounds__(256) void k_attn(const u16* __restrict__ Qb,
                                              const u16* __restrict__ Kb,
                                              const u16* __restrict__ Vt,
                                              const float* __restrict__ mask,
                                              u16* __restrict__ Ctx) {
  __shared__ u16 Kl[2][64 * 64];   // [key][d]   128B rows, 16B-slot XOR (row&7)
  __shared__ u16 Vl[2][64 * 64];   // [d][key]   128B rows, 16B-slot XOR (row&7)

  int tid = threadIdx.x;
  int lane = tid & 63, wv = tid >> 6;
  int l16 = lane & 15, lg = lane >> 4;
  int bh = blockIdx.y, b = bh / H_, h = bh % H_;
  int qw0 = blockIdx.x * 64 + wv * 16;

  int qr = qw0 + l16; if (qr > S_ - 1) qr = S_ - 1;
  const u16* qp = Qb + ((size_t)(b * S_ + qr)) * D_ + h * HD_ + lg * 8;
  bf16x8 aq0 = *(const bf16x8*)(qp);
  bf16x8 aq1 = *(const bf16x8*)(qp + 32);
  const float* mrow = mask + (size_t)b * S_ * S_ + (size_t)qr * S_;

  // staging constants: dest rows wv*16 + i*8 + (lane>>3); row&7 == lane>>3
  int sr0 = wv * 16 + (lane >> 3);
  int csw = ((lane & 7) ^ (lane >> 3)) * 8;  // inverse-swizzled source elem offset
  const u16* ksrc = Kb + (size_t)b * S_ * D_ + h * HD_ + csw;
  const u16* vsrc0 = Vt + ((size_t)bh * HD_ + sr0) * SPAD + csw;
  const u16* vsrc1 = vsrc0 + 8 * SPAD;

  float m_ = BIGNEG, l_ = 0.0f;
  f32x4 acc[4] = {};
  const f32x4 zf = {0, 0, 0, 0};
  float4 mvs[4];
  int sx = (l16 & 7) << 4;

#define STAGE(k0s, bufb) do {                                          \
    int key0_ = (k0s) + sr0;     if (key0_ > S_ - 1) key0_ = S_ - 1;   \
    int key1_ = key0_ + 8;       if (key1_ > S_ - 1) key1_ = S_ - 1;   \
    u16* kd_ = &Kl[bufb][0] + wv * 1024;                               \
    u16* vd_ = &Vl[bufb][0] + wv * 1024;                               \
    gl_lds16(ksrc + (size_t)key0_ * D_, kd_);                          \
    gl_lds16(ksrc + (size_t)key1_ * D_, kd_ + 512);                    \
    gl_lds16(vsrc0 + (k0s), vd_);                                      \
    gl_lds16(vsrc1 + (k0s), vd_ + 512);                                \
  } while (0)

#define COMPUTE(curb, LASTV) do {                                      \
    const u16* KlC = &Kl[curb][0];                                     \
    const u16* VlC = &Vl[curb][0];                                     \
    f32x4 s[4];                                                        \
    __builtin_amdgcn_s_setprio(1);                                     \
    _Pragma("unroll")                                                  \
    for (int sub = 0; sub < 4; sub++) {                                \
      const u16* kb = KlC + (sub * 16 + l16) * 64;                     \
      bf16x8 kf0 = *(const bf16x8*)(kb + ((lg     ^ (l16 & 7)) * 8));  \
      bf16x8 kf1 = *(const bf16x8*)(kb + (((4+lg) ^ (l16 & 7)) * 8));  \
      s[sub] = MFMA(kf0, aq0, zf, 0, 0, 0);                            \
      s[sub] = MFMA(kf1, aq1, s[sub], 0, 0, 0);                        \
    }                                                                  \
    __builtin_amdgcn_s_setprio(0);                                     \
    _Pragma("unroll")                                                  \
    for (int sub = 0; sub < 4; sub++) {                                \
      s[sub][0] = fmaf(mvs[sub].x, LOG2E, s[sub][0]);                  \
      s[sub][1] = fmaf(mvs[sub].y, LOG2E, s[sub][1]);                  \
      s[sub][2] = fmaf(mvs[sub].z, LOG2E, s[sub][2]);                  \
      s[sub][3] = fmaf(mvs[sub].w, LOG2E, s[sub][3]);                  \
    }                                                                  \
    if (LASTV) {                                                       \
      _Pragma("unroll")                                                \
      for (int sub = 0; sub < 4; sub++) {                              \
        int kb_ = 1472 + sub * 16 + lg * 4;                            \
        _Pragma("unroll")                                              \
        for (int j = 0; j < 4; j++)                                    \
          if (kb_ + j >= S_) s[sub][j] = BIGNEG;                       \
      }                                                                \
    }                                                                  \
    float t0 = fmaxf(fmaxf(s[0][0], s[0][1]), fmaxf(s[0][2], s[0][3]));\
    float t1 = fmaxf(fmaxf(s[1][0], s[1][1]), fmaxf(s[1][2], s[1][3]));\
    float t2 = fmaxf(fmaxf(s[2][0], s[2][1]), fmaxf(s[2][2], s[2][3]));\
    float t3 = fmaxf(fmaxf(s[3][0], s[3][1]), fmaxf(s[3][2], s[3][3]));\
    float rmax = fmaxf(fmaxf(t0, t1), fmaxf(t2, t3));                  \
    rmax = fmaxf(rmax, __shfl_xor(rmax, 16));                          \
    rmax = fmaxf(rmax, __shfl_xor(rmax, 32));                          \
    float mn = fmaxf(m_, rmax);                                        \
    if (!__all(mn - m_ <= 8.0f)) {                                     \
      float c = __builtin_amdgcn_exp2f(m_ - mn);                       \
      m_ = mn; l_ *= c;                                                \
      _Pragma("unroll")                                                \
      for (int j = 0; j < 4; j++) {                                    \
        float cj = __shfl(c, lg * 4 + j);                              \
        acc[0][j] *= cj; acc[1][j] *= cj;                              \
        acc[2][j] *= cj; acc[3][j] *= cj;                              \
      }                                                                \
    }                                                                  \
    _Pragma("unroll")                                                  \
    for (int sub = 0; sub < 4; sub++)                                  \
      _Pragma("unroll")                                                \
      for (int j = 0; j < 4; j++)                                      \
        s[sub][j] = __builtin_amdgcn_exp2f(s[sub][j] - m_);            \
    float a0 = (s[0][0] + s[0][1]) + (s[0][2] + s[0][3]);              \
    float a1 = (s[1][0] + s[1][1]) + (s[1][2] + s[1][3]);              \
    float a2 = (s[2][0] + s[2][1]) + (s[2][2] + s[2][3]);              \
    float a3 = (s[3][0] + s[3][1]) + (s[3][2] + s[3][3]);              \
    float rs = (a0 + a1) + (a2 + a3);                                  \
    rs += __shfl_xor(rs, 16);                                          \
    rs += __shfl_xor(rs, 32);                                          \
    l_ += rs;                                                          \
    union { u32x4v u; bf16x8 bf; } pc0, pc1;                           \
    pc0.u[0] = cvtpk(s[0][0], s[0][1]); pc0.u[1] = cvtpk(s[0][2], s[0][3]); \
    pc0.u[2] = cvtpk(s[1][0], s[1][1]); pc0.u[3] = cvtpk(s[1][2], s[1][3]); \
    pc1.u[0] = cvtpk(s[2][0], s[2][1]); pc1.u[1] = cvtpk(s[2][2], s[2][3]); \
    pc1.u[2] = cvtpk(s[3][0], s[3][1]); pc1.u[3] = cvtpk(s[3][2], s[3][3]); \
    __builtin_amdgcn_s_setprio(1);                                     \
    _Pragma("unroll")                                                  \
    for (int n = 0; n < 4; n++) {                                      \
      const char* rb = (const char*)VlC + (n * 16 + l16) * 128;        \
      union { uint2 q[2]; bf16x8 bf; } bv0u, bv1u;                     \
      bv0u.q[0] = *(const uint2*)(rb + ((lg * 8     ) ^ sx));          \
      bv0u.q[1] = *(const uint2*)(rb + ((lg * 8 + 32) ^ sx));          \
      bv1u.q[0] = *(const uint2*)(rb + ((lg * 8 + 64) ^ sx));          \
      bv1u.q[1] = *(const uint2*)(rb + ((lg * 8 + 96) ^ sx));          \
      acc[n] = MFMA(pc0.bf, bv0u.bf, acc[n], 0, 0, 0);                 \
      acc[n] = MFMA(pc1.bf, bv1u.bf, acc[n], 0, 0, 0);                 \
    }                                                                  \
    __builtin_amdgcn_s_setprio(0);                                     \
  } while (0)

  STAGE(0, 0);

  for (int t = 0; t < NTA - 1; t++) {
    int k0 = t * KVB;
    #pragma unroll
    for (int sub = 0; sub < 4; sub++)
      mvs[sub] = *(const float4*)(mrow + k0 + sub * 16 + lg * 4);
    __builtin_amdgcn_s_barrier();
    asm volatile("" ::: "memory");
    STAGE(k0 + KVB, (t + 1) & 1);
    asm volatile("s_waitcnt vmcnt(4)" ::: "memory");
    __builtin_amdgcn_s_barrier();
    asm volatile("" ::: "memory");
    COMPUTE(t & 1, false);
  }
  {
    const int k0 = (NTA - 1) * KVB;   // 1472, tail = 28 keys
    #pragma unroll
    for (int sub = 0; sub < 4; sub++) {
      int mc = k0 + sub * 16 + lg * 4; if (mc > S_ - 4) mc = S_ - 4;
      mvs[sub] = *(const float4*)(mrow + mc);
    }
    __builtin_amdgcn_s_barrier();
    asm volatile("s_waitcnt vmcnt(0)" ::: "memory");
    __builtin_amdgcn_s_barrier();
    asm volatile("" ::: "memory");
    COMPUTE((NTA - 1) & 1, true);
  }

  float inv = 1.0f / l_;
  #pragma unroll
  for (int j = 0; j < 4; j++) {
    float invj = __shfl(inv, lg * 4 + j);
    int row = qw0 + lg * 4 + j;
    if (row < S_) {
      #pragma unroll
      for (int n = 0; n < 4; n++) {
        float v = acc[n][j] * invj;
        Ctx[((size_t)(b * S_ + row)) * D_ + h * HD_ + n * 16 + l16] = f2bf(v);
      }
    }
  }
#undef STAGE
#undef COMPUTE
}

extern "C" void kernel_launch(void* const* d_in, const int* in_sizes, int n_in,
                              void* d_out, int out_size, void* d_ws, size_t ws_size,
                              hipStream_t stream) {
  const float* hs   = (const float*)d_in[0];
  const float* mask = (const float*)d_in[1];
  const float* q_w  = (const float*)d_in[2];
  const float* q_b  = (const float*)d_in[3];
  const float* k_w  = (const float*)d_in[4];
  const float* v_b  = (const float*)d_in[6];
  const float* v_w  = (const float*)d_in[5];
  const float* o_w  = (const float*)d_in[7];
  const float* o_b  = (const float*)d_in[8];
  float* out = (float*)d_out;

  char* w = (char*)d_ws;
  const size_t XD = (size_t)M_ * D_;
  const size_t WD = (size_t)D_ * D_;
  u16* Xb  = (u16*)(w);                 w += XD * 2;
  u16* Wtq = (u16*)(w);                 w += WD * 2;   // q,k,v,o contiguous
  u16* Wtk = (u16*)(w);                 w += WD * 2;
  u16* Wtv = (u16*)(w);                 w += WD * 2;
  u16* Wto = (u16*)(w);                 w += WD * 2;
  u16* Qb  = (u16*)(w);                 w += XD * 2;   // q,k,v outputs contiguous
  u16* Kb  = (u16*)(w);                 w += XD * 2;
  u16* Vb  = (u16*)(w);                 w += XD * 2;
  u16* Vt  = (u16*)(w);                 w += (size_t)B_ * H_ * HD_ * SPAD * 2;
  u16* Ctx = Xb;   // alias: Xb dead after QKV projection
  (void)Wtk; (void)Wtv; (void)Kb; (void)Vb;

  k_conv<<<dim3(3750), dim3(256), 0, stream>>>(hs, Xb);
  k_trans4<<<dim3(40, 40, 4), dim3(256), 0, stream>>>(q_w, k_w, v_w, o_w, Wtq);

  k_gemmqkv<<<dim3(47, 30), dim3(256), 0, stream>>>(Xb, Wtq, q_b, v_b, Qb);
  k_vtrans<<<dim3(80, 12), dim3(256), 0, stream>>>(Vb, Vt);

  k_attn<<<dim3(24, 80), dim3(256), 0, stream>>>(Qb, Kb, Vt, mask, Ctx);

  k_gemmo<<<dim3(47, 10), dim3(256), 0, stream>>>(Ctx, Wto, o_b, out);
}